// Round 6
// baseline (1371.959 us; speedup 1.0000x reference)
//
#include <hip/hip_runtime.h>
#include <cstdint>
#include <cstddef>

#define T_   10
#define B_   128
#define CH_  512
#define N_   16
#define H_   16
#define HID_ 2048
#define TB_  (T_ * B_)       // 1280 (t,b) slabs

#define EP_QKV  0   // u16 t-masks scattered to q/k/v pk buffers in scan layout
#define EP_SPK  1   // u16 t-masks, [b][row*16+tok] (sproj packed)
#define EP_HS   2   // u16 t-masks, [b*16+tok][2048] (hsT packed)
#define EP_OUT  3   // fp32 out = x + sproj + spike (per-t, required layout)

typedef __attribute__((ext_vector_type(8))) short bf16x8;
typedef __attribute__((ext_vector_type(4))) float f32x4;
typedef unsigned short u16;
typedef unsigned long long u64;

__device__ __forceinline__ short f2b(float f) {      // fp32 -> bf16 bits, RNE
    uint32_t u = __float_as_uint(f);
    return (short)((u + 0x7FFFu + ((u >> 16) & 1u)) >> 16);
}
__device__ __forceinline__ float b2f(short s) {
    return __uint_as_float(((uint32_t)(uint16_t)s) << 16);
}

// ---------------------------------------------------------------------------
// Fold BN (+opt conv bias) into weights; emit bf16 hi/lo, [m][K] k-contig.
// ---------------------------------------------------------------------------
__global__ void fold2(const float* __restrict__ W, const float* __restrict__ bnp,
                      const float* __restrict__ eb, int M, int K, int o0,
                      short* __restrict__ Ah, short* __restrict__ Al,
                      float* __restrict__ bias) {
    int idx = blockIdx.x * 256 + threadIdx.x;
    if (idx >= M * K) return;
    int o = idx / K, k = idx - o * K;
    float g  = bnp[o];
    float be = bnp[M + o];
    float mu = bnp[2 * M + o];
    float va = bnp[3 * M + o];
    float inv = g * (1.0f / sqrtf(va + 1e-5f));
    float w = W[idx] * inv;
    short h = f2b(w);
    Ah[(size_t)(o0 + o) * K + k] = h;
    Al[(size_t)(o0 + o) * K + k] = f2b(w - b2f(h));
    if (k == 0) bias[o0 + o] = ((eb ? eb[o] : 0.0f) - mu) * inv + be;
}

// ---------------------------------------------------------------------------
// One-shot fp32 (+opt packed-spike add, bit t) -> bf16 hi/lo split, T-layout
// [slab*16+n][512] (k-contiguous). Bitwise-identical to the in-GEMM split.
// ---------------------------------------------------------------------------
__global__ __launch_bounds__(256) void splitx(
    const float* __restrict__ X, const u16* __restrict__ S,
    short* __restrict__ Bh, short* __restrict__ Bl) {
    __shared__ float xs[8192];
    const int slab = blockIdx.x;
    const int tid  = threadIdx.x;
    const int t    = slab / B_;
    const int b    = slab - t * B_;
    const float* xp = X + (size_t)slab * 8192;
    for (int i = tid; i < 2048; i += 256) {
        float4 v = *(const float4*)&xp[i * 4];
        if (S) {
            union { u16 s[4]; uint2 v; } sw;
            sw.v = *(const uint2*)&S[(size_t)b * 8192 + i * 4];
            v.x += (float)((sw.s[0] >> t) & 1);
            v.y += (float)((sw.s[1] >> t) & 1);
            v.z += (float)((sw.s[2] >> t) & 1);
            v.w += (float)((sw.s[3] >> t) & 1);
        }
        *(float4*)&xs[i * 4] = v;
    }
    __syncthreads();
    const int n = tid & 15, kc = tid >> 4;   // row token n, k-chunk of 32
    size_t orow = ((size_t)slab * 16 + n) * 512 + kc * 32;
#pragma unroll
    for (int i8 = 0; i8 < 4; ++i8) {
        union { short s[8]; uint4 v; } hb, lb;
#pragma unroll
        for (int j = 0; j < 8; ++j) {
            float v = xs[(kc * 32 + i8 * 8 + j) * 16 + n];
            short h = f2b(v);
            hb.s[j] = h;
            lb.s[j] = f2b(v - b2f(h));
        }
        *(uint4*)&Bh[orow + i8 * 8] = hb.v;
        *(uint4*)&Bl[orow + i8 * 8] = lb.v;
    }
}

// ---------------------------------------------------------------------------
// BF16T GEMM, t-phase staged: per phase stage ONE t's full-K B panel into
// LDS (pitch 40 shorts/row, slab pad +8 -> conflict-minimal reads AND
// writes), then a barrier-free 16-step K-loop. 10 barrier-pairs per kernel
// instead of 32, and no wave ever waits on staging inside the K-loop.
// Accumulation order per acc[r][t] identical to previous rounds (k
// ascending; ah*bh, al*bh, ah*bl) -> bitwise identical results.
// XCD swizzle (round 5) kept: all GX row-blocks of one b on one XCD.
// ---------------------------------------------------------------------------
template <int R, int GX, int EPI>
__global__ __launch_bounds__(256, 2) void gemm_bf16t(
    const short* __restrict__ Ah, const short* __restrict__ Al,
    const float* __restrict__ bias,
    const short* __restrict__ Bh, const short* __restrict__ Bl,
    u16* __restrict__ O0, u16* __restrict__ O1, u16* __restrict__ O2) {
    constexpr int KT  = 512;
    constexpr int SLB = 648;                 // shorts per kc32-slab (16*40 + 8)
    __shared__ __align__(16) short BsH[16 * SLB];
    __shared__ __align__(16) short BsL[16 * SLB];
    const int tid  = threadIdx.x;
    const int lane = tid & 63;
    const int wv   = tid >> 6;
    const int fid  = blockIdx.x;
    const int xcd  = fid & 7;
    const int slot = fid >> 3;
    const int brow = slot / GX;
    const int xb   = slot - brow * GX;
    const int b    = (brow << 3) | xcd;
    const int l15  = lane & 15;
    const int q    = lane >> 4;
    const int row0 = xb * (R * 64) + wv * (R * 16);

    f32x4 acc[R][10];
#pragma unroll
    for (int r = 0; r < R; ++r)
#pragma unroll
        for (int t = 0; t < 10; ++t) acc[r][t] = 0.0f;

#pragma unroll
    for (int p = 0; p < 10; ++p) {
        __syncthreads();
        // ---- stage t=p full-K panel: 16n x 64 chunks of 8 ----
        for (int idx = tid; idx < 1024; idx += 256) {
            int c8 = idx & 63, n = idx >> 6;
            size_t g = ((size_t)(p * B_ + b) * 16 + n) * KT + c8 * 8;
            int lo = (c8 >> 2) * SLB + n * 40 + (c8 & 3) * 8;
            *(uint4*)&BsH[lo] = *(const uint4*)&Bh[g];
            *(uint4*)&BsL[lo] = *(const uint4*)&Bl[g];
        }
        __syncthreads();
        // ---- barrier-free K-loop over this t ----
#pragma unroll
        for (int kk = 0; kk < 16; ++kk) {
            const int k0 = kk * 32;
            bf16x8 ah[R], al[R];
#pragma unroll
            for (int r = 0; r < R; ++r) {
                size_t ga = (size_t)(row0 + r * 16 + l15) * KT + k0 + q * 8;
                ah[r] = *(const bf16x8*)&Ah[ga];
                al[r] = *(const bf16x8*)&Al[ga];
            }
            bf16x8 bh = *(const bf16x8*)&BsH[kk * SLB + l15 * 40 + q * 8];
            bf16x8 bl = *(const bf16x8*)&BsL[kk * SLB + l15 * 40 + q * 8];
#pragma unroll
            for (int r = 0; r < R; ++r) {
                acc[r][p] = __builtin_amdgcn_mfma_f32_16x16x32_bf16(ah[r], bh, acc[r][p], 0, 0, 0);
                acc[r][p] = __builtin_amdgcn_mfma_f32_16x16x32_bf16(al[r], bh, acc[r][p], 0, 0, 0);
                acc[r][p] = __builtin_amdgcn_mfma_f32_16x16x32_bf16(ah[r], bl, acc[r][p], 0, 0, 0);
            }
        }
    }

    // ---- epilogue: lane holds (row = q*4+reg, tok = l15) x all 10 t ----
    const int tok = l15;
#pragma unroll
    for (int r = 0; r < R; ++r) {
        u16 m4[4];
#pragma unroll
        for (int reg = 0; reg < 4; ++reg) {
            const int row = row0 + r * 16 + q * 4 + reg;
            const float bsv = bias[row];
            float mem = 0.0f;
            u16 msk = 0;
#pragma unroll
            for (int t = 0; t < 10; ++t) {
                float u = acc[r][t][reg] + bsv;
                mem += (u - mem) * 0.5f;
                bool s = mem > 1.0f;
                if (s) mem = 0.0f;
                msk |= (u16)((s ? 1u : 0u) << t);
            }
            if constexpr (EPI == EP_QKV) {
                int tsr = row >> 9;
                int c   = row & 511;
                int hh  = (c & 31) >> 1;
                int dd  = ((c & 1) << 4) | tok;
                int nn  = c >> 5;
                u16* qp = (tsr == 0) ? O0 : ((tsr == 1) ? O1 : O2);
                qp[(size_t)b * 8192 + (size_t)hh * 512 + dd * 16 + nn] = msk;
            } else {  // EP_HS
                m4[reg] = msk;
            }
        }
        if constexpr (EPI == EP_HS) {
            union { u16 s[4]; uint2 v; } pk;
            pk.s[0] = m4[0]; pk.s[1] = m4[1]; pk.s[2] = m4[2]; pk.s[3] = m4[3];
            *(uint2*)&O0[((size_t)b * 16 + tok) * 2048 + row0 + r * 16 + q * 4] = pk.v;
        }
    }
}

// ---------------------------------------------------------------------------
// PKT GEMM, zero-barrier K-loop: the whole packed B panel [16n][K] u16
// (16/64 KB) is loaded into LDS once ([kc][n][8] u16, slab stride 136 ->
// uniform bank distribution), ONE barrier, then the K-loop is
// ds_read_b128 + per-lane bit-extract + MFMA with no synchronization at
// all -- waves free-run and hide all load latency. Extraction uses the
// packed-u32 trick ((w>>t)&0x00010001)*0x3F80 = two bf16 lanes in 3 ops;
// produces exactly the same 0/0x3F80 values as before.
// ---------------------------------------------------------------------------
template <int R, int GX, int EPI, int KT>
__global__ __launch_bounds__(256, 2) void gemm_pkt(
    const short* __restrict__ Ah, const short* __restrict__ Al,
    const float* __restrict__ bias, const u16* __restrict__ Bu,
    u16* __restrict__ O0, float* __restrict__ Oout,
    const float* __restrict__ Xr, const u16* __restrict__ Sr) {
    constexpr int K8 = KT / 8;
    __shared__ __align__(16) u16 Bp[K8 * 136];
    const int tid  = threadIdx.x;
    const int lane = tid & 63;
    const int wv   = tid >> 6;
    const int fid  = blockIdx.x;
    const int xcd  = fid & 7;
    const int slot = fid >> 3;
    const int brow = slot / GX;
    const int xb   = slot - brow * GX;
    const int b    = (brow << 3) | xcd;
    const int l15  = lane & 15;
    const int q    = lane >> 4;
    const int row0 = xb * (R * 64) + wv * (R * 16);

    // ---- fill packed B panel into LDS (once) ----
    for (int idx = tid; idx < 16 * K8; idx += 256) {
        int kc = idx & (K8 - 1), n = idx / K8;
        *(uint4*)&Bp[kc * 136 + n * 8] =
            *(const uint4*)&Bu[((size_t)b * 16 + n) * KT + kc * 8];
    }
    __syncthreads();   // the only barrier

    f32x4 acc[R][10];
#pragma unroll
    for (int r = 0; r < R; ++r)
#pragma unroll
        for (int t = 0; t < 10; ++t) acc[r][t] = 0.0f;

    for (int k0 = 0; k0 < KT; k0 += 32) {
        bf16x8 ah[R], al[R];
#pragma unroll
        for (int r = 0; r < R; ++r) {
            size_t ga = (size_t)(row0 + r * 16 + l15) * KT + k0 + q * 8;
            ah[r] = *(const bf16x8*)&Ah[ga];
            al[r] = *(const bf16x8*)&Al[ga];
        }
        union { uint32_t u[4]; uint4 v; } w;
        w.v = *(const uint4*)&Bp[(k0 / 8 + q) * 136 + l15 * 8];
#pragma unroll
        for (int t = 0; t < 10; ++t) {
            union { uint32_t u[4]; bf16x8 h; } bh;
#pragma unroll
            for (int j = 0; j < 4; ++j)
                bh.u[j] = ((w.u[j] >> t) & 0x00010001u) * 0x3F80u;
#pragma unroll
            for (int r = 0; r < R; ++r) {
                acc[r][t] = __builtin_amdgcn_mfma_f32_16x16x32_bf16(ah[r], bh.h, acc[r][t], 0, 0, 0);
                acc[r][t] = __builtin_amdgcn_mfma_f32_16x16x32_bf16(al[r], bh.h, acc[r][t], 0, 0, 0);
            }
        }
    }

    // ---- epilogue ----
    const int tok = l15;
#pragma unroll
    for (int r = 0; r < R; ++r) {
#pragma unroll
        for (int reg = 0; reg < 4; ++reg) {
            const int row = row0 + r * 16 + q * 4 + reg;
            const float bsv = bias[row];
            u16 sv = 0;
            if constexpr (EPI == EP_OUT) sv = Sr[(size_t)b * 8192 + (size_t)row * 16 + tok];
            float mem = 0.0f;
            u16 msk = 0;
#pragma unroll
            for (int t = 0; t < 10; ++t) {
                float u = acc[r][t][reg] + bsv;
                mem += (u - mem) * 0.5f;
                bool s = mem > 1.0f;
                if (s) mem = 0.0f;
                msk |= (u16)((s ? 1u : 0u) << t);
                if constexpr (EPI == EP_OUT) {
                    size_t off = (size_t)(t * B_ + b) * 8192 + (size_t)row * 16 + tok;
                    Oout[off] = Xr[off] + (float)((sv >> t) & 1) + (s ? 1.0f : 0.0f);
                }
            }
            if constexpr (EPI == EP_SPK) {
                O0[(size_t)b * 8192 + (size_t)row * 16 + tok] = msk;
            }
        }
    }
}

// ---------------------------------------------------------------------------
// Temporal scan v5: t-bit-packed I/O, static-index conv, and
// __launch_bounds__(256, 1) so wreg[80] stays in VGPRs (the (256,2) builds
// were pinned at 128 VGPRs and spilled 380 MB of scratch traffic).
// ---------------------------------------------------------------------------
__global__ __launch_bounds__(256, 1) void scan_kernel(
    const u16* __restrict__ qs, const u16* __restrict__ ks,
    const u16* __restrict__ vs, const float* __restrict__ tiw,
    const float* __restrict__ tib, u16* __restrict__ y1pk) {
    __shared__ float qS[4][36 * 20];   // [d+2][m] spike carry, halo rows = 0
    __shared__ float kS[4][32 * 20];
    __shared__ float vS[4][32 * 20];
    __shared__ float qbS[4][32 * 20];
    __shared__ float A[4][16 * 17];
    const int l  = threadIdx.x & 63;
    const int w  = threadIdx.x >> 6;
    const int b  = blockIdx.y;
    const int h  = blockIdx.x * 4 + w;
    const int n  = l & 15, dg = l >> 4;
    float* qSw  = qS[w];
    float* kSw  = kS[w];
    float* vSw  = vS[w];
    float* qbSw = qbS[w];
    float* Aw   = A[w];

    float wreg[80];
#pragma unroll
    for (int j = 0; j < 80; ++j) wreg[j] = tiw[n * 80 + j];
    const float tibr = tib[n];

    if (l < 40) { qSw[l] = 0.0f; qSw[680 + l] = 0.0f; }

    const size_t base = (size_t)b * 8192 + (size_t)h * 512 + (size_t)l * 8;
    union { u16 s[8]; uint4 v; } qw, kw, vw;
    qw.v = *(const uint4*)&qs[base];
    kw.v = *(const uint4*)&ks[base];
    vw.v = *(const uint4*)&vs[base];

#pragma unroll
    for (int j = 0; j < 8; ++j) {
        int f = l * 8 + j, d = f >> 4, m = f & 15;
        qSw[(d + 2) * 20 + m] = (float)(qw.s[j] & 1);
        kSw[d * 20 + m]       = (float)(kw.s[j] & 1);
        vSw[d * 20 + m]       = (float)(vw.s[j] & 1);
    }

    float mem1[8] = {}, mem2[8] = {}, mem3[8] = {};
    u16 ym[8] = {};

    auto attn_step = [&](int t) {
        float dots[4] = {0.0f, 0.0f, 0.0f, 0.0f};
#pragma unroll
        for (int d = 0; d < 32; ++d) {
            float qv = qSw[(d + 2) * 20 + n];
#pragma unroll
            for (int jj = 0; jj < 4; ++jj)
                dots[jj] = fmaf(qv, kSw[d * 20 + dg * 4 + jj], dots[jj]);
        }
#pragma unroll
        for (int jj = 0; jj < 4; ++jj) Aw[n * 17 + dg * 4 + jj] = dots[jj] * 0.25f;
        float o[8] = {};
#pragma unroll
        for (int m = 0; m < 16; ++m) {
            float av = Aw[n * 17 + m];
#pragma unroll
            for (int dd = 0; dd < 8; ++dd)
                o[dd] = fmaf(av, vSw[(dg * 8 + dd) * 20 + m], o[dd]);
        }
#pragma unroll
        for (int dd = 0; dd < 8; ++dd) {
            mem3[dd] += (o[dd] - mem3[dd]) * 0.5f;
            bool s3 = mem3[dd] > 1.0f;
            if (s3) mem3[dd] = 0.0f;
            ym[dd] |= (u16)((s3 ? 1u : 0u) << t);
        }
    };

    attn_step(0);

    for (int t = 1; t < T_; ++t) {
#pragma unroll
        for (int j = 0; j < 8; ++j) {
            int f = l * 8 + j, d = f >> 4, m = f & 15;
            qbSw[d * 20 + m] = (float)((qw.s[j] >> t) & 1);
            kSw[d * 20 + m]  = (float)((kw.s[j] >> t) & 1);
            vSw[d * 20 + m]  = (float)((vw.s[j] >> t) & 1);
        }
        float c[8];
#pragma unroll
        for (int dd = 0; dd < 8; ++dd) c[dd] = tibr;
#pragma unroll
        for (int x = 0; x < 12; ++x) {
            const float* rp = &qSw[(dg * 8 + x) * 20];
            float qrow[16];
            *(float4*)&qrow[0]  = *(const float4*)&rp[0];
            *(float4*)&qrow[4]  = *(const float4*)&rp[4];
            *(float4*)&qrow[8]  = *(const float4*)&rp[8];
            *(float4*)&qrow[12] = *(const float4*)&rp[12];
#pragma unroll
            for (int k = 0; k < 5; ++k) {
                const int o = x - k;
                if (o >= 0 && o < 8) {
#pragma unroll
                    for (int i = 0; i < 16; ++i)
                        c[o] = fmaf(wreg[i * 5 + k], qrow[i], c[o]);
                }
            }
        }
#pragma unroll
        for (int dd = 0; dd < 8; ++dd) {
            mem1[dd] += (c[dd] - mem1[dd]) * 0.5f;
            bool s1 = mem1[dd] > 1.0f;
            if (s1) mem1[dd] = 0.0f;
            float qb = qbSw[(dg * 8 + dd) * 20 + n];
            float mix = 0.5f * (s1 ? 1.0f : 0.0f) + 0.5f * qb;
            mem2[dd] += (mix - mem2[dd]) * 0.5f;
            bool s2 = mem2[dd] > 1.0f;
            if (s2) mem2[dd] = 0.0f;
            qSw[(dg * 8 + dd + 2) * 20 + n] = s2 ? 1.0f : 0.0f;
        }
        attn_step(t);
    }

    union { u16 s[8]; uint4 v; } yv;
#pragma unroll
    for (int dd = 0; dd < 8; ++dd) yv.s[dd] = ym[dd];
    *(uint4*)&y1pk[((size_t)b * 16 + n) * 512 + h * 32 + dg * 8] = yv.v;
}

// ---------------------------------------------------------------------------
extern "C" void kernel_launch(void* const* d_in, const int* in_sizes, int n_in,
                              void* d_out, int out_size, void* d_ws, size_t ws_size,
                              hipStream_t stream) {
    const float* x    = (const float*)d_in[0];
    const float* Wq   = (const float*)d_in[1];
    const float* Wk   = (const float*)d_in[2];
    const float* Wv   = (const float*)d_in[3];
    const float* Wp   = (const float*)d_in[4];
    const float* bnq  = (const float*)d_in[5];
    const float* bnk  = (const float*)d_in[6];
    const float* bnv  = (const float*)d_in[7];
    const float* bnpj = (const float*)d_in[8];
    const float* tiw  = (const float*)d_in[9];
    const float* tib  = (const float*)d_in[10];
    const float* W1   = (const float*)d_in[11];
    const float* b1   = (const float*)d_in[12];
    const float* bn1  = (const float*)d_in[13];
    const float* W2   = (const float*)d_in[14];
    const float* b2   = (const float*)d_in[15];
    const float* bn2  = (const float*)d_in[16];
    float* out = (float*)d_out;

    char* ws = (char*)d_ws;
    size_t cur = 0;
    auto alloc = [&](size_t bytes) -> void* {
        void* p = ws + cur;
        cur = (cur + bytes + 255) & ~(size_t)255;
        return p;
    };
    const size_t PKQ = (size_t)B_ * 8192;          // u16 elems per packed tensor (2 MB)
    u16* qpk  = (u16*)alloc(4 * PKQ * 2);
    u16* kpk  = qpk + PKQ;
    u16* vpk  = qpk + 2 * PKQ;
    u16* y1pk = qpk + 3 * PKQ;
    u16* hspk = qpk;                                // [b*16+n][2048] u16 = 4*PKQ
    u16* spk  = (u16*)alloc(PKQ * 2);               // sproj packed, 2 MB
    short* BhT = (short*)alloc((size_t)TB_ * 16 * 512 * 2);  // 21 MB
    short* BlT = (short*)alloc((size_t)TB_ * 16 * 512 * 2);  // 21 MB
    short* Ah_qkv = (short*)alloc((size_t)1536 * 512 * 2);
    short* Al_qkv = (short*)alloc((size_t)1536 * 512 * 2);
    short* Ah_p   = (short*)alloc((size_t)512 * 512 * 2);
    short* Al_p   = (short*)alloc((size_t)512 * 512 * 2);
    short* Ah_1   = (short*)alloc((size_t)2048 * 512 * 2);
    short* Al_1   = (short*)alloc((size_t)2048 * 512 * 2);
    short* Ah_2   = (short*)alloc((size_t)512 * 2048 * 2);
    short* Al_2   = (short*)alloc((size_t)512 * 2048 * 2);
    float* bs_qkv = (float*)alloc(1536 * 4);
    float* bs_p   = (float*)alloc(512 * 4);
    float* bs_1   = (float*)alloc(2048 * 4);
    float* bs_2   = (float*)alloc(512 * 4);
    // total ~65 MB

    // --- prep: fold BN, split bf16 hi/lo, [m][K] ---
    fold2<<<1024, 256, 0, stream>>>(Wq, bnq, nullptr, 512, 512, 0,    Ah_qkv, Al_qkv, bs_qkv);
    fold2<<<1024, 256, 0, stream>>>(Wk, bnk, nullptr, 512, 512, 512,  Ah_qkv, Al_qkv, bs_qkv);
    fold2<<<1024, 256, 0, stream>>>(Wv, bnv, nullptr, 512, 512, 1024, Ah_qkv, Al_qkv, bs_qkv);
    fold2<<<1024, 256, 0, stream>>>(Wp, bnpj, nullptr, 512, 512, 0,   Ah_p, Al_p, bs_p);
    fold2<<<4096, 256, 0, stream>>>(W1, bn1, b1, 2048, 512, 0,        Ah_1, Al_1, bs_1);
    fold2<<<4096, 256, 0, stream>>>(W2, bn2, b2, 512, 2048, 0,        Ah_2, Al_2, bs_2);

    // --- SSA ---
    splitx<<<TB_, 256, 0, stream>>>(x, nullptr, BhT, BlT);
    gemm_bf16t<4, 6, EP_QKV><<<6 * B_, 256, 0, stream>>>(
        Ah_qkv, Al_qkv, bs_qkv, BhT, BlT, qpk, kpk, vpk);
    scan_kernel<<<dim3(4, B_), 256, 0, stream>>>(qpk, kpk, vpk, tiw, tib, y1pk);
    gemm_pkt<2, 4, EP_SPK, 512><<<4 * B_, 256, 0, stream>>>(
        Ah_p, Al_p, bs_p, y1pk, spk, nullptr, nullptr, nullptr);

    // --- MLP ---  (x2 = x + sproj pre-split once, reusing BhT/BlT)
    splitx<<<TB_, 256, 0, stream>>>(x, spk, BhT, BlT);
    gemm_bf16t<4, 8, EP_HS><<<8 * B_, 256, 0, stream>>>(
        Ah_1, Al_1, bs_1, BhT, BlT, hspk, nullptr, nullptr);
    gemm_pkt<2, 4, EP_OUT, 2048><<<4 * B_, 256, 0, stream>>>(
        Ah_2, Al_2, bs_2, hspk, nullptr, out, x, spk);
}

// Round 7
// 572.374 us; speedup vs baseline: 2.3970x; 2.3970x over previous
//
#include <hip/hip_runtime.h>
#include <cstdint>
#include <cstddef>

#define T_   10
#define B_   128
#define CH_  512
#define N_   16
#define H_   16
#define HID_ 2048
#define TB_  (T_ * B_)       // 1280 (t,b) slabs

#define EP_QKV  0   // u16 t-masks scattered to q/k/v pk buffers in scan layout
#define EP_SPK  1   // u16 t-masks, [b][row*16+tok] (sproj packed)
#define EP_HS   2   // u16 t-masks, [b*16+tok][2048] (hsT packed)
#define EP_OUT  3   // fp32 out = x + sproj + spike (per-t, required layout)

typedef __attribute__((ext_vector_type(8))) short bf16x8;
typedef __attribute__((ext_vector_type(4))) float f32x4;
typedef unsigned short u16;
typedef unsigned long long u64;

__device__ __forceinline__ short f2b(float f) {      // fp32 -> bf16 bits, RNE
    uint32_t u = __float_as_uint(f);
    return (short)((u + 0x7FFFu + ((u >> 16) & 1u)) >> 16);
}
__device__ __forceinline__ float b2f(short s) {
    return __uint_as_float(((uint32_t)(uint16_t)s) << 16);
}

// ---------------------------------------------------------------------------
// Fold BN (+opt conv bias) into weights; emit bf16 hi/lo, [m][K] k-contig.
// ---------------------------------------------------------------------------
__global__ void fold2(const float* __restrict__ W, const float* __restrict__ bnp,
                      const float* __restrict__ eb, int M, int K, int o0,
                      short* __restrict__ Ah, short* __restrict__ Al,
                      float* __restrict__ bias) {
    int idx = blockIdx.x * 256 + threadIdx.x;
    if (idx >= M * K) return;
    int o = idx / K, k = idx - o * K;
    float g  = bnp[o];
    float be = bnp[M + o];
    float mu = bnp[2 * M + o];
    float va = bnp[3 * M + o];
    float inv = g * (1.0f / sqrtf(va + 1e-5f));
    float w = W[idx] * inv;
    short h = f2b(w);
    Ah[(size_t)(o0 + o) * K + k] = h;
    Al[(size_t)(o0 + o) * K + k] = f2b(w - b2f(h));
    if (k == 0) bias[o0 + o] = ((eb ? eb[o] : 0.0f) - mu) * inv + be;
}

// ---------------------------------------------------------------------------
// One-shot fp32 (+opt packed-spike add, bit t) -> bf16 hi/lo split, T-layout
// [slab*16+n][512] (k-contiguous). Bitwise-identical to the in-GEMM split.
// ---------------------------------------------------------------------------
__global__ __launch_bounds__(256) void splitx(
    const float* __restrict__ X, const u16* __restrict__ S,
    short* __restrict__ Bh, short* __restrict__ Bl) {
    __shared__ float xs[8192];
    const int slab = blockIdx.x;
    const int tid  = threadIdx.x;
    const int t    = slab / B_;
    const int b    = slab - t * B_;
    const float* xp = X + (size_t)slab * 8192;
    for (int i = tid; i < 2048; i += 256) {
        float4 v = *(const float4*)&xp[i * 4];
        if (S) {
            union { u16 s[4]; uint2 v; } sw;
            sw.v = *(const uint2*)&S[(size_t)b * 8192 + i * 4];
            v.x += (float)((sw.s[0] >> t) & 1);
            v.y += (float)((sw.s[1] >> t) & 1);
            v.z += (float)((sw.s[2] >> t) & 1);
            v.w += (float)((sw.s[3] >> t) & 1);
        }
        *(float4*)&xs[i * 4] = v;
    }
    __syncthreads();
    const int n = tid & 15, kc = tid >> 4;   // row token n, k-chunk of 32
    size_t orow = ((size_t)slab * 16 + n) * 512 + kc * 32;
#pragma unroll
    for (int i8 = 0; i8 < 4; ++i8) {
        union { short s[8]; uint4 v; } hb, lb;
#pragma unroll
        for (int j = 0; j < 8; ++j) {
            float v = xs[(kc * 32 + i8 * 8 + j) * 16 + n];
            short h = f2b(v);
            hb.s[j] = h;
            lb.s[j] = f2b(v - b2f(h));
        }
        *(uint4*)&Bh[orow + i8 * 8] = hb.v;
        *(uint4*)&Bl[orow + i8 * 8] = lb.v;
    }
}

// ---------------------------------------------------------------------------
// BF16T GEMM: round-5 k0-outer structure (proven 146us, bitwise-passing,
// A stays in a narrow L2-hot k-window) + T14 async-STAGE split: next
// k-chunk's B prefetched into REGISTERS during the MFMA phase, so between
// the two barriers only fast ds_writes remain -- the HBM/L2 load latency
// that round-5 exposed between barriers now overlaps compute. Staged
// values, MFMA order, epilogue all unchanged -> bitwise identical.
// (Round-6's t-phase variant is reverted: it blew the 128-VGPR cap AND
// broke the lockstep k-window, refetching A 10x from HBM = 264 MB.)
// ---------------------------------------------------------------------------
template <int R, int GX, int EPI>
__global__ __launch_bounds__(256, 2) void gemm_bf16t(
    const short* __restrict__ Ah, const short* __restrict__ Al,
    const float* __restrict__ bias,
    const short* __restrict__ Bh, const short* __restrict__ Bl,
    u16* __restrict__ O0, u16* __restrict__ O1, u16* __restrict__ O2) {
    constexpr int KT = 512;
    __shared__ __align__(16) short BsH[6400];   // [t][n][k32], pitch 40
    __shared__ __align__(16) short BsL[6400];
    const int tid  = threadIdx.x;
    const int lane = tid & 63;
    const int wv   = tid >> 6;
    const int fid  = blockIdx.x;
    const int xcd  = fid & 7;
    const int slot = fid >> 3;
    const int brow = slot / GX;
    const int xb   = slot - brow * GX;
    const int b    = (brow << 3) | xcd;
    const int l15  = lane & 15;
    const int q    = lane >> 4;
    const int row0 = xb * (R * 64) + wv * (R * 16);

    // staging chunk ids for this thread (640 x 16B chunks per k-step)
    const int i0 = tid, i1 = tid + 256, i2 = tid + 512;   // i2 only if tid<128
    auto gaddr = [&](int idx, int k0) -> size_t {
        int qu = idx & 3, n = (idx >> 2) & 15, t = idx >> 6;
        return ((size_t)(t * B_ + b) * 16 + n) * KT + k0 + qu * 8;
    };
    auto laddr = [&](int idx) -> int {
        int qu = idx & 3, n = (idx >> 2) & 15, t = idx >> 6;
        return (t * 16 + n) * 40 + qu * 8;
    };

    f32x4 acc[R][10];
#pragma unroll
    for (int r = 0; r < R; ++r)
#pragma unroll
        for (int t = 0; t < 10; ++t) acc[r][t] = 0.0f;

    // ---- prologue prefetch (k0 = 0) ----
    uint4 ph0, ph1, ph2, pl0, pl1, pl2;
    ph0 = *(const uint4*)&Bh[gaddr(i0, 0)];
    pl0 = *(const uint4*)&Bl[gaddr(i0, 0)];
    ph1 = *(const uint4*)&Bh[gaddr(i1, 0)];
    pl1 = *(const uint4*)&Bl[gaddr(i1, 0)];
    if (tid < 128) {
        ph2 = *(const uint4*)&Bh[gaddr(i2, 0)];
        pl2 = *(const uint4*)&Bl[gaddr(i2, 0)];
    }

    for (int k0 = 0; k0 < KT; k0 += 32) {
        __syncthreads();
        // ---- commit prefetched chunk to LDS (fast: ds_write only) ----
        *(uint4*)&BsH[laddr(i0)] = ph0;
        *(uint4*)&BsL[laddr(i0)] = pl0;
        *(uint4*)&BsH[laddr(i1)] = ph1;
        *(uint4*)&BsL[laddr(i1)] = pl1;
        if (tid < 128) {
            *(uint4*)&BsH[laddr(i2)] = ph2;
            *(uint4*)&BsL[laddr(i2)] = pl2;
        }
        __syncthreads();
        // ---- issue next chunk's loads; latency hides under MFMA ----
        if (k0 + 32 < KT) {
            ph0 = *(const uint4*)&Bh[gaddr(i0, k0 + 32)];
            pl0 = *(const uint4*)&Bl[gaddr(i0, k0 + 32)];
            ph1 = *(const uint4*)&Bh[gaddr(i1, k0 + 32)];
            pl1 = *(const uint4*)&Bl[gaddr(i1, k0 + 32)];
            if (tid < 128) {
                ph2 = *(const uint4*)&Bh[gaddr(i2, k0 + 32)];
                pl2 = *(const uint4*)&Bl[gaddr(i2, k0 + 32)];
            }
        }
        // ---- A fragments (L2-resident, lockstep k-window) ----
        bf16x8 ah[R], al[R];
#pragma unroll
        for (int r = 0; r < R; ++r) {
            size_t ga = (size_t)(row0 + r * 16 + l15) * KT + k0 + q * 8;
            ah[r] = *(const bf16x8*)&Ah[ga];
            al[r] = *(const bf16x8*)&Al[ga];
        }
        // ---- MFMA over 10 t ----
#pragma unroll
        for (int t = 0; t < 10; ++t) {
            bf16x8 bh = *(const bf16x8*)&BsH[(t * 16 + l15) * 40 + q * 8];
            bf16x8 bl = *(const bf16x8*)&BsL[(t * 16 + l15) * 40 + q * 8];
#pragma unroll
            for (int r = 0; r < R; ++r) {
                acc[r][t] = __builtin_amdgcn_mfma_f32_16x16x32_bf16(ah[r], bh, acc[r][t], 0, 0, 0);
                acc[r][t] = __builtin_amdgcn_mfma_f32_16x16x32_bf16(al[r], bh, acc[r][t], 0, 0, 0);
                acc[r][t] = __builtin_amdgcn_mfma_f32_16x16x32_bf16(ah[r], bl, acc[r][t], 0, 0, 0);
            }
        }
    }

    // ---- epilogue: lane holds (row = q*4+reg, tok = l15) x all 10 t ----
    const int tok = l15;
#pragma unroll
    for (int r = 0; r < R; ++r) {
        u16 m4[4];
#pragma unroll
        for (int reg = 0; reg < 4; ++reg) {
            const int row = row0 + r * 16 + q * 4 + reg;
            const float bsv = bias[row];
            float mem = 0.0f;
            u16 msk = 0;
#pragma unroll
            for (int t = 0; t < 10; ++t) {
                float u = acc[r][t][reg] + bsv;
                mem += (u - mem) * 0.5f;
                bool s = mem > 1.0f;
                if (s) mem = 0.0f;
                msk |= (u16)((s ? 1u : 0u) << t);
            }
            if constexpr (EPI == EP_QKV) {
                int tsr = row >> 9;
                int c   = row & 511;
                int hh  = (c & 31) >> 1;
                int dd  = ((c & 1) << 4) | tok;
                int nn  = c >> 5;
                u16* qp = (tsr == 0) ? O0 : ((tsr == 1) ? O1 : O2);
                qp[(size_t)b * 8192 + (size_t)hh * 512 + dd * 16 + nn] = msk;
            } else {  // EP_HS
                m4[reg] = msk;
            }
        }
        if constexpr (EPI == EP_HS) {
            union { u16 s[4]; uint2 v; } pk;
            pk.s[0] = m4[0]; pk.s[1] = m4[1]; pk.s[2] = m4[2]; pk.s[3] = m4[3];
            *(uint2*)&O0[((size_t)b * 16 + tok) * 2048 + row0 + r * 16 + q * 4] = pk.v;
        }
    }
}

// ---------------------------------------------------------------------------
// PKT GEMM, zero-barrier K-loop (round-6, proven): whole packed B panel
// [16n][K] u16 in LDS once ([kc][n][8] u16, slab stride 136), ONE barrier,
// then ds_read_b128 + bit-extract + MFMA with no synchronization -- waves
// free-run and hide all load latency. ((w>>t)&0x00010001)*0x3F80 produces
// exactly the same 0/0x3F80 bf16 values as before.
// ---------------------------------------------------------------------------
template <int R, int GX, int EPI, int KT>
__global__ __launch_bounds__(256, 2) void gemm_pkt(
    const short* __restrict__ Ah, const short* __restrict__ Al,
    const float* __restrict__ bias, const u16* __restrict__ Bu,
    u16* __restrict__ O0, float* __restrict__ Oout,
    const float* __restrict__ Xr, const u16* __restrict__ Sr) {
    constexpr int K8 = KT / 8;
    __shared__ __align__(16) u16 Bp[K8 * 136];
    const int tid  = threadIdx.x;
    const int lane = tid & 63;
    const int wv   = tid >> 6;
    const int fid  = blockIdx.x;
    const int xcd  = fid & 7;
    const int slot = fid >> 3;
    const int brow = slot / GX;
    const int xb   = slot - brow * GX;
    const int b    = (brow << 3) | xcd;
    const int l15  = lane & 15;
    const int q    = lane >> 4;
    const int row0 = xb * (R * 64) + wv * (R * 16);

    // ---- fill packed B panel into LDS (once) ----
    for (int idx = tid; idx < 16 * K8; idx += 256) {
        int kc = idx & (K8 - 1), n = idx / K8;
        *(uint4*)&Bp[kc * 136 + n * 8] =
            *(const uint4*)&Bu[((size_t)b * 16 + n) * KT + kc * 8];
    }
    __syncthreads();   // the only barrier

    f32x4 acc[R][10];
#pragma unroll
    for (int r = 0; r < R; ++r)
#pragma unroll
        for (int t = 0; t < 10; ++t) acc[r][t] = 0.0f;

    for (int k0 = 0; k0 < KT; k0 += 32) {
        bf16x8 ah[R], al[R];
#pragma unroll
        for (int r = 0; r < R; ++r) {
            size_t ga = (size_t)(row0 + r * 16 + l15) * KT + k0 + q * 8;
            ah[r] = *(const bf16x8*)&Ah[ga];
            al[r] = *(const bf16x8*)&Al[ga];
        }
        union { uint32_t u[4]; uint4 v; } w;
        w.v = *(const uint4*)&Bp[(k0 / 8 + q) * 136 + l15 * 8];
#pragma unroll
        for (int t = 0; t < 10; ++t) {
            union { uint32_t u[4]; bf16x8 h; } bh;
#pragma unroll
            for (int j = 0; j < 4; ++j)
                bh.u[j] = ((w.u[j] >> t) & 0x00010001u) * 0x3F80u;
#pragma unroll
            for (int r = 0; r < R; ++r) {
                acc[r][t] = __builtin_amdgcn_mfma_f32_16x16x32_bf16(ah[r], bh.h, acc[r][t], 0, 0, 0);
                acc[r][t] = __builtin_amdgcn_mfma_f32_16x16x32_bf16(al[r], bh.h, acc[r][t], 0, 0, 0);
            }
        }
    }

    // ---- epilogue ----
    const int tok = l15;
#pragma unroll
    for (int r = 0; r < R; ++r) {
#pragma unroll
        for (int reg = 0; reg < 4; ++reg) {
            const int row = row0 + r * 16 + q * 4 + reg;
            const float bsv = bias[row];
            u16 sv = 0;
            if constexpr (EPI == EP_OUT) sv = Sr[(size_t)b * 8192 + (size_t)row * 16 + tok];
            float mem = 0.0f;
            u16 msk = 0;
#pragma unroll
            for (int t = 0; t < 10; ++t) {
                float u = acc[r][t][reg] + bsv;
                mem += (u - mem) * 0.5f;
                bool s = mem > 1.0f;
                if (s) mem = 0.0f;
                msk |= (u16)((s ? 1u : 0u) << t);
                if constexpr (EPI == EP_OUT) {
                    size_t off = (size_t)(t * B_ + b) * 8192 + (size_t)row * 16 + tok;
                    Oout[off] = Xr[off] + (float)((sv >> t) & 1) + (s ? 1.0f : 0.0f);
                }
            }
            if constexpr (EPI == EP_SPK) {
                O0[(size_t)b * 8192 + (size_t)row * 16 + tok] = msk;
            }
        }
    }
}

// ---------------------------------------------------------------------------
// Temporal scan v5: t-bit-packed I/O, static-index conv, and
// __launch_bounds__(256, 1) so wreg[80] stays in VGPRs (the (256,2) builds
// were pinned at 128 VGPRs and spilled 380 MB of scratch traffic).
// ---------------------------------------------------------------------------
__global__ __launch_bounds__(256, 1) void scan_kernel(
    const u16* __restrict__ qs, const u16* __restrict__ ks,
    const u16* __restrict__ vs, const float* __restrict__ tiw,
    const float* __restrict__ tib, u16* __restrict__ y1pk) {
    __shared__ float qS[4][36 * 20];   // [d+2][m] spike carry, halo rows = 0
    __shared__ float kS[4][32 * 20];
    __shared__ float vS[4][32 * 20];
    __shared__ float qbS[4][32 * 20];
    __shared__ float A[4][16 * 17];
    const int l  = threadIdx.x & 63;
    const int w  = threadIdx.x >> 6;
    const int b  = blockIdx.y;
    const int h  = blockIdx.x * 4 + w;
    const int n  = l & 15, dg = l >> 4;
    float* qSw  = qS[w];
    float* kSw  = kS[w];
    float* vSw  = vS[w];
    float* qbSw = qbS[w];
    float* Aw   = A[w];

    float wreg[80];
#pragma unroll
    for (int j = 0; j < 80; ++j) wreg[j] = tiw[n * 80 + j];
    const float tibr = tib[n];

    if (l < 40) { qSw[l] = 0.0f; qSw[680 + l] = 0.0f; }

    const size_t base = (size_t)b * 8192 + (size_t)h * 512 + (size_t)l * 8;
    union { u16 s[8]; uint4 v; } qw, kw, vw;
    qw.v = *(const uint4*)&qs[base];
    kw.v = *(const uint4*)&ks[base];
    vw.v = *(const uint4*)&vs[base];

#pragma unroll
    for (int j = 0; j < 8; ++j) {
        int f = l * 8 + j, d = f >> 4, m = f & 15;
        qSw[(d + 2) * 20 + m] = (float)(qw.s[j] & 1);
        kSw[d * 20 + m]       = (float)(kw.s[j] & 1);
        vSw[d * 20 + m]       = (float)(vw.s[j] & 1);
    }

    float mem1[8] = {}, mem2[8] = {}, mem3[8] = {};
    u16 ym[8] = {};

    auto attn_step = [&](int t) {
        float dots[4] = {0.0f, 0.0f, 0.0f, 0.0f};
#pragma unroll
        for (int d = 0; d < 32; ++d) {
            float qv = qSw[(d + 2) * 20 + n];
#pragma unroll
            for (int jj = 0; jj < 4; ++jj)
                dots[jj] = fmaf(qv, kSw[d * 20 + dg * 4 + jj], dots[jj]);
        }
#pragma unroll
        for (int jj = 0; jj < 4; ++jj) Aw[n * 17 + dg * 4 + jj] = dots[jj] * 0.25f;
        float o[8] = {};
#pragma unroll
        for (int m = 0; m < 16; ++m) {
            float av = Aw[n * 17 + m];
#pragma unroll
            for (int dd = 0; dd < 8; ++dd)
                o[dd] = fmaf(av, vSw[(dg * 8 + dd) * 20 + m], o[dd]);
        }
#pragma unroll
        for (int dd = 0; dd < 8; ++dd) {
            mem3[dd] += (o[dd] - mem3[dd]) * 0.5f;
            bool s3 = mem3[dd] > 1.0f;
            if (s3) mem3[dd] = 0.0f;
            ym[dd] |= (u16)((s3 ? 1u : 0u) << t);
        }
    };

    attn_step(0);

    for (int t = 1; t < T_; ++t) {
#pragma unroll
        for (int j = 0; j < 8; ++j) {
            int f = l * 8 + j, d = f >> 4, m = f & 15;
            qbSw[d * 20 + m] = (float)((qw.s[j] >> t) & 1);
            kSw[d * 20 + m]  = (float)((kw.s[j] >> t) & 1);
            vSw[d * 20 + m]  = (float)((vw.s[j] >> t) & 1);
        }
        float c[8];
#pragma unroll
        for (int dd = 0; dd < 8; ++dd) c[dd] = tibr;
#pragma unroll
        for (int x = 0; x < 12; ++x) {
            const float* rp = &qSw[(dg * 8 + x) * 20];
            float qrow[16];
            *(float4*)&qrow[0]  = *(const float4*)&rp[0];
            *(float4*)&qrow[4]  = *(const float4*)&rp[4];
            *(float4*)&qrow[8]  = *(const float4*)&rp[8];
            *(float4*)&qrow[12] = *(const float4*)&rp[12];
#pragma unroll
            for (int k = 0; k < 5; ++k) {
                const int o = x - k;
                if (o >= 0 && o < 8) {
#pragma unroll
                    for (int i = 0; i < 16; ++i)
                        c[o] = fmaf(wreg[i * 5 + k], qrow[i], c[o]);
                }
            }
        }
#pragma unroll
        for (int dd = 0; dd < 8; ++dd) {
            mem1[dd] += (c[dd] - mem1[dd]) * 0.5f;
            bool s1 = mem1[dd] > 1.0f;
            if (s1) mem1[dd] = 0.0f;
            float qb = qbSw[(dg * 8 + dd) * 20 + n];
            float mix = 0.5f * (s1 ? 1.0f : 0.0f) + 0.5f * qb;
            mem2[dd] += (mix - mem2[dd]) * 0.5f;
            bool s2 = mem2[dd] > 1.0f;
            if (s2) mem2[dd] = 0.0f;
            qSw[(dg * 8 + dd + 2) * 20 + n] = s2 ? 1.0f : 0.0f;
        }
        attn_step(t);
    }

    union { u16 s[8]; uint4 v; } yv;
#pragma unroll
    for (int dd = 0; dd < 8; ++dd) yv.s[dd] = ym[dd];
    *(uint4*)&y1pk[((size_t)b * 16 + n) * 512 + h * 32 + dg * 8] = yv.v;
}

// ---------------------------------------------------------------------------
extern "C" void kernel_launch(void* const* d_in, const int* in_sizes, int n_in,
                              void* d_out, int out_size, void* d_ws, size_t ws_size,
                              hipStream_t stream) {
    const float* x    = (const float*)d_in[0];
    const float* Wq   = (const float*)d_in[1];
    const float* Wk   = (const float*)d_in[2];
    const float* Wv   = (const float*)d_in[3];
    const float* Wp   = (const float*)d_in[4];
    const float* bnq  = (const float*)d_in[5];
    const float* bnk  = (const float*)d_in[6];
    const float* bnv  = (const float*)d_in[7];
    const float* bnpj = (const float*)d_in[8];
    const float* tiw  = (const float*)d_in[9];
    const float* tib  = (const float*)d_in[10];
    const float* W1   = (const float*)d_in[11];
    const float* b1   = (const float*)d_in[12];
    const float* bn1  = (const float*)d_in[13];
    const float* W2   = (const float*)d_in[14];
    const float* b2   = (const float*)d_in[15];
    const float* bn2  = (const float*)d_in[16];
    float* out = (float*)d_out;

    char* ws = (char*)d_ws;
    size_t cur = 0;
    auto alloc = [&](size_t bytes) -> void* {
        void* p = ws + cur;
        cur = (cur + bytes + 255) & ~(size_t)255;
        return p;
    };
    const size_t PKQ = (size_t)B_ * 8192;          // u16 elems per packed tensor (2 MB)
    u16* qpk  = (u16*)alloc(4 * PKQ * 2);
    u16* kpk  = qpk + PKQ;
    u16* vpk  = qpk + 2 * PKQ;
    u16* y1pk = qpk + 3 * PKQ;
    u16* hspk = qpk;                                // [b*16+n][2048] u16 = 4*PKQ
    u16* spk  = (u16*)alloc(PKQ * 2);               // sproj packed, 2 MB
    short* BhT = (short*)alloc((size_t)TB_ * 16 * 512 * 2);  // 21 MB
    short* BlT = (short*)alloc((size_t)TB_ * 16 * 512 * 2);  // 21 MB
    short* Ah_qkv = (short*)alloc((size_t)1536 * 512 * 2);
    short* Al_qkv = (short*)alloc((size_t)1536 * 512 * 2);
    short* Ah_p   = (short*)alloc((size_t)512 * 512 * 2);
    short* Al_p   = (short*)alloc((size_t)512 * 512 * 2);
    short* Ah_1   = (short*)alloc((size_t)2048 * 512 * 2);
    short* Al_1   = (short*)alloc((size_t)2048 * 512 * 2);
    short* Ah_2   = (short*)alloc((size_t)512 * 2048 * 2);
    short* Al_2   = (short*)alloc((size_t)512 * 2048 * 2);
    float* bs_qkv = (float*)alloc(1536 * 4);
    float* bs_p   = (float*)alloc(512 * 4);
    float* bs_1   = (float*)alloc(2048 * 4);
    float* bs_2   = (float*)alloc(512 * 4);
    // total ~65 MB

    // --- prep: fold BN, split bf16 hi/lo, [m][K] ---
    fold2<<<1024, 256, 0, stream>>>(Wq, bnq, nullptr, 512, 512, 0,    Ah_qkv, Al_qkv, bs_qkv);
    fold2<<<1024, 256, 0, stream>>>(Wk, bnk, nullptr, 512, 512, 512,  Ah_qkv, Al_qkv, bs_qkv);
    fold2<<<1024, 256, 0, stream>>>(Wv, bnv, nullptr, 512, 512, 1024, Ah_qkv, Al_qkv, bs_qkv);
    fold2<<<1024, 256, 0, stream>>>(Wp, bnpj, nullptr, 512, 512, 0,   Ah_p, Al_p, bs_p);
    fold2<<<4096, 256, 0, stream>>>(W1, bn1, b1, 2048, 512, 0,        Ah_1, Al_1, bs_1);
    fold2<<<4096, 256, 0, stream>>>(W2, bn2, b2, 512, 2048, 0,        Ah_2, Al_2, bs_2);

    // --- SSA ---
    splitx<<<TB_, 256, 0, stream>>>(x, nullptr, BhT, BlT);
    gemm_bf16t<4, 6, EP_QKV><<<6 * B_, 256, 0, stream>>>(
        Ah_qkv, Al_qkv, bs_qkv, BhT, BlT, qpk, kpk, vpk);
    scan_kernel<<<dim3(4, B_), 256, 0, stream>>>(qpk, kpk, vpk, tiw, tib, y1pk);
    gemm_pkt<2, 4, EP_SPK, 512><<<4 * B_, 256, 0, stream>>>(
        Ah_p, Al_p, bs_p, y1pk, spk, nullptr, nullptr, nullptr);

    // --- MLP ---  (x2 = x + sproj pre-split once, reusing BhT/BlT)
    splitx<<<TB_, 256, 0, stream>>>(x, spk, BhT, BlT);
    gemm_bf16t<4, 8, EP_HS><<<8 * B_, 256, 0, stream>>>(
        Ah_1, Al_1, bs_1, BhT, BlT, hspk, nullptr, nullptr);
    gemm_pkt<2, 4, EP_OUT, 2048><<<4 * B_, 256, 0, stream>>>(
        Ah_2, Al_2, bs_2, hspk, nullptr, out, x, spk);
}

// Round 8
// 570.211 us; speedup vs baseline: 2.4061x; 1.0038x over previous
//
#include <hip/hip_runtime.h>
#include <cstdint>
#include <cstddef>

#define T_   10
#define B_   128
#define CH_  512
#define N_   16
#define H_   16
#define HID_ 2048
#define TB_  (T_ * B_)       // 1280 (t,b) slabs

#define EP_QKV  0   // u16 t-masks scattered to q/k/v pk buffers in scan layout
#define EP_SPK  1   // u16 t-masks, [b][row*16+tok] (sproj packed)
#define EP_HS   2   // u16 t-masks, [b*16+tok][2048] (hsT packed)
#define EP_OUT  3   // fp32 out = x + sproj + spike (per-t, required layout)

typedef __attribute__((ext_vector_type(8))) short bf16x8;
typedef __attribute__((ext_vector_type(4))) float f32x4;
typedef unsigned short u16;
typedef unsigned long long u64;

__device__ __forceinline__ short f2b(float f) {      // fp32 -> bf16 bits, RNE
    uint32_t u = __float_as_uint(f);
    return (short)((u + 0x7FFFu + ((u >> 16) & 1u)) >> 16);
}
__device__ __forceinline__ float b2f(short s) {
    return __uint_as_float(((uint32_t)(uint16_t)s) << 16);
}

// ---------------------------------------------------------------------------
// Fold BN (+opt conv bias) into weights; emit bf16 hi/lo, [m][K] k-contig.
// ---------------------------------------------------------------------------
__global__ void fold2(const float* __restrict__ W, const float* __restrict__ bnp,
                      const float* __restrict__ eb, int M, int K, int o0,
                      short* __restrict__ Ah, short* __restrict__ Al,
                      float* __restrict__ bias) {
    int idx = blockIdx.x * 256 + threadIdx.x;
    if (idx >= M * K) return;
    int o = idx / K, k = idx - o * K;
    float g  = bnp[o];
    float be = bnp[M + o];
    float mu = bnp[2 * M + o];
    float va = bnp[3 * M + o];
    float inv = g * (1.0f / sqrtf(va + 1e-5f));
    float w = W[idx] * inv;
    short h = f2b(w);
    Ah[(size_t)(o0 + o) * K + k] = h;
    Al[(size_t)(o0 + o) * K + k] = f2b(w - b2f(h));
    if (k == 0) bias[o0 + o] = ((eb ? eb[o] : 0.0f) - mu) * inv + be;
}

// ---------------------------------------------------------------------------
// One-shot fp32 (+opt packed-spike add, bit t) -> bf16 hi/lo split, T-layout
// [slab*16+n][512] (k-contiguous). Bitwise-identical to the in-GEMM split.
// ---------------------------------------------------------------------------
__global__ __launch_bounds__(256) void splitx(
    const float* __restrict__ X, const u16* __restrict__ S,
    short* __restrict__ Bh, short* __restrict__ Bl) {
    __shared__ float xs[8192];
    const int slab = blockIdx.x;
    const int tid  = threadIdx.x;
    const int t    = slab / B_;
    const int b    = slab - t * B_;
    const float* xp = X + (size_t)slab * 8192;
    for (int i = tid; i < 2048; i += 256) {
        float4 v = *(const float4*)&xp[i * 4];
        if (S) {
            union { u16 s[4]; uint2 v; } sw;
            sw.v = *(const uint2*)&S[(size_t)b * 8192 + i * 4];
            v.x += (float)((sw.s[0] >> t) & 1);
            v.y += (float)((sw.s[1] >> t) & 1);
            v.z += (float)((sw.s[2] >> t) & 1);
            v.w += (float)((sw.s[3] >> t) & 1);
        }
        *(float4*)&xs[i * 4] = v;
    }
    __syncthreads();
    const int n = tid & 15, kc = tid >> 4;   // row token n, k-chunk of 32
    size_t orow = ((size_t)slab * 16 + n) * 512 + kc * 32;
#pragma unroll
    for (int i8 = 0; i8 < 4; ++i8) {
        union { short s[8]; uint4 v; } hb, lb;
#pragma unroll
        for (int j = 0; j < 8; ++j) {
            float v = xs[(kc * 32 + i8 * 8 + j) * 16 + n];
            short h = f2b(v);
            hb.s[j] = h;
            lb.s[j] = f2b(v - b2f(h));
        }
        *(uint4*)&Bh[orow + i8 * 8] = hb.v;
        *(uint4*)&Bl[orow + i8 * 8] = lb.v;
    }
}

// ---------------------------------------------------------------------------
// BF16T GEMM: k0-outer lockstep loop + register prefetch (round 7) with
// R=2 tiles (round 8): round-7's R=4 used 160 AGPR (acc) + 128 VGPR = 288
// unified regs/thread -> only ONE block/CU resident (8 waves x 288 > 2048
// pool), so each block's barrier/staging latency was fully exposed
// (130us vs ~50us MFMA floor). R=2 halves acc to 80 AGPR (~180 total),
// two blocks/CU co-resident, cross-block overlap hides the stalls.
// Same rows, same k-order, same 3-MFMA hi/lo sequence -> bitwise identical.
// ---------------------------------------------------------------------------
template <int R, int GX, int EPI>
__global__ __launch_bounds__(256, 2) void gemm_bf16t(
    const short* __restrict__ Ah, const short* __restrict__ Al,
    const float* __restrict__ bias,
    const short* __restrict__ Bh, const short* __restrict__ Bl,
    u16* __restrict__ O0, u16* __restrict__ O1, u16* __restrict__ O2) {
    constexpr int KT = 512;
    __shared__ __align__(16) short BsH[6400];   // [t][n][k32], pitch 40
    __shared__ __align__(16) short BsL[6400];
    const int tid  = threadIdx.x;
    const int lane = tid & 63;
    const int wv   = tid >> 6;
    const int fid  = blockIdx.x;
    const int xcd  = fid & 7;
    const int slot = fid >> 3;
    const int brow = slot / GX;
    const int xb   = slot - brow * GX;
    const int b    = (brow << 3) | xcd;
    const int l15  = lane & 15;
    const int q    = lane >> 4;
    const int row0 = xb * (R * 64) + wv * (R * 16);

    // staging chunk ids for this thread (640 x 16B chunks per k-step)
    const int i0 = tid, i1 = tid + 256, i2 = tid + 512;   // i2 only if tid<128
    auto gaddr = [&](int idx, int k0) -> size_t {
        int qu = idx & 3, n = (idx >> 2) & 15, t = idx >> 6;
        return ((size_t)(t * B_ + b) * 16 + n) * KT + k0 + qu * 8;
    };
    auto laddr = [&](int idx) -> int {
        int qu = idx & 3, n = (idx >> 2) & 15, t = idx >> 6;
        return (t * 16 + n) * 40 + qu * 8;
    };

    f32x4 acc[R][10];
#pragma unroll
    for (int r = 0; r < R; ++r)
#pragma unroll
        for (int t = 0; t < 10; ++t) acc[r][t] = 0.0f;

    // ---- prologue prefetch (k0 = 0) ----
    uint4 ph0, ph1, ph2, pl0, pl1, pl2;
    ph0 = *(const uint4*)&Bh[gaddr(i0, 0)];
    pl0 = *(const uint4*)&Bl[gaddr(i0, 0)];
    ph1 = *(const uint4*)&Bh[gaddr(i1, 0)];
    pl1 = *(const uint4*)&Bl[gaddr(i1, 0)];
    if (tid < 128) {
        ph2 = *(const uint4*)&Bh[gaddr(i2, 0)];
        pl2 = *(const uint4*)&Bl[gaddr(i2, 0)];
    }

    for (int k0 = 0; k0 < KT; k0 += 32) {
        __syncthreads();
        // ---- commit prefetched chunk to LDS (fast: ds_write only) ----
        *(uint4*)&BsH[laddr(i0)] = ph0;
        *(uint4*)&BsL[laddr(i0)] = pl0;
        *(uint4*)&BsH[laddr(i1)] = ph1;
        *(uint4*)&BsL[laddr(i1)] = pl1;
        if (tid < 128) {
            *(uint4*)&BsH[laddr(i2)] = ph2;
            *(uint4*)&BsL[laddr(i2)] = pl2;
        }
        __syncthreads();
        // ---- issue next chunk's loads; latency hides under MFMA ----
        if (k0 + 32 < KT) {
            ph0 = *(const uint4*)&Bh[gaddr(i0, k0 + 32)];
            pl0 = *(const uint4*)&Bl[gaddr(i0, k0 + 32)];
            ph1 = *(const uint4*)&Bh[gaddr(i1, k0 + 32)];
            pl1 = *(const uint4*)&Bl[gaddr(i1, k0 + 32)];
            if (tid < 128) {
                ph2 = *(const uint4*)&Bh[gaddr(i2, k0 + 32)];
                pl2 = *(const uint4*)&Bl[gaddr(i2, k0 + 32)];
            }
        }
        // ---- A fragments (L2-resident, lockstep k-window) ----
        bf16x8 ah[R], al[R];
#pragma unroll
        for (int r = 0; r < R; ++r) {
            size_t ga = (size_t)(row0 + r * 16 + l15) * KT + k0 + q * 8;
            ah[r] = *(const bf16x8*)&Ah[ga];
            al[r] = *(const bf16x8*)&Al[ga];
        }
        // ---- MFMA over 10 t ----
#pragma unroll
        for (int t = 0; t < 10; ++t) {
            bf16x8 bh = *(const bf16x8*)&BsH[(t * 16 + l15) * 40 + q * 8];
            bf16x8 bl = *(const bf16x8*)&BsL[(t * 16 + l15) * 40 + q * 8];
#pragma unroll
            for (int r = 0; r < R; ++r) {
                acc[r][t] = __builtin_amdgcn_mfma_f32_16x16x32_bf16(ah[r], bh, acc[r][t], 0, 0, 0);
                acc[r][t] = __builtin_amdgcn_mfma_f32_16x16x32_bf16(al[r], bh, acc[r][t], 0, 0, 0);
                acc[r][t] = __builtin_amdgcn_mfma_f32_16x16x32_bf16(ah[r], bl, acc[r][t], 0, 0, 0);
            }
        }
    }

    // ---- epilogue: lane holds (row = q*4+reg, tok = l15) x all 10 t ----
    const int tok = l15;
#pragma unroll
    for (int r = 0; r < R; ++r) {
        u16 m4[4];
#pragma unroll
        for (int reg = 0; reg < 4; ++reg) {
            const int row = row0 + r * 16 + q * 4 + reg;
            const float bsv = bias[row];
            float mem = 0.0f;
            u16 msk = 0;
#pragma unroll
            for (int t = 0; t < 10; ++t) {
                float u = acc[r][t][reg] + bsv;
                mem += (u - mem) * 0.5f;
                bool s = mem > 1.0f;
                if (s) mem = 0.0f;
                msk |= (u16)((s ? 1u : 0u) << t);
            }
            if constexpr (EPI == EP_QKV) {
                int tsr = row >> 9;
                int c   = row & 511;
                int hh  = (c & 31) >> 1;
                int dd  = ((c & 1) << 4) | tok;
                int nn  = c >> 5;
                u16* qp = (tsr == 0) ? O0 : ((tsr == 1) ? O1 : O2);
                qp[(size_t)b * 8192 + (size_t)hh * 512 + dd * 16 + nn] = msk;
            } else {  // EP_HS
                m4[reg] = msk;
            }
        }
        if constexpr (EPI == EP_HS) {
            union { u16 s[4]; uint2 v; } pk;
            pk.s[0] = m4[0]; pk.s[1] = m4[1]; pk.s[2] = m4[2]; pk.s[3] = m4[3];
            *(uint2*)&O0[((size_t)b * 16 + tok) * 2048 + row0 + r * 16 + q * 4] = pk.v;
        }
    }
}

// ---------------------------------------------------------------------------
// PKT GEMM, zero-barrier K-loop (round-6, proven): whole packed B panel
// [16n][K] u16 in LDS once ([kc][n][8] u16, slab stride 136), ONE barrier,
// then ds_read_b128 + bit-extract + MFMA with no synchronization -- waves
// free-run and hide all load latency. ((w>>t)&0x00010001)*0x3F80 produces
// exactly the same 0/0x3F80 bf16 values as before.
// ---------------------------------------------------------------------------
template <int R, int GX, int EPI, int KT>
__global__ __launch_bounds__(256, 2) void gemm_pkt(
    const short* __restrict__ Ah, const short* __restrict__ Al,
    const float* __restrict__ bias, const u16* __restrict__ Bu,
    u16* __restrict__ O0, float* __restrict__ Oout,
    const float* __restrict__ Xr, const u16* __restrict__ Sr) {
    constexpr int K8 = KT / 8;
    __shared__ __align__(16) u16 Bp[K8 * 136];
    const int tid  = threadIdx.x;
    const int lane = tid & 63;
    const int wv   = tid >> 6;
    const int fid  = blockIdx.x;
    const int xcd  = fid & 7;
    const int slot = fid >> 3;
    const int brow = slot / GX;
    const int xb   = slot - brow * GX;
    const int b    = (brow << 3) | xcd;
    const int l15  = lane & 15;
    const int q    = lane >> 4;
    const int row0 = xb * (R * 64) + wv * (R * 16);

    // ---- fill packed B panel into LDS (once) ----
    for (int idx = tid; idx < 16 * K8; idx += 256) {
        int kc = idx & (K8 - 1), n = idx / K8;
        *(uint4*)&Bp[kc * 136 + n * 8] =
            *(const uint4*)&Bu[((size_t)b * 16 + n) * KT + kc * 8];
    }
    __syncthreads();   // the only barrier

    f32x4 acc[R][10];
#pragma unroll
    for (int r = 0; r < R; ++r)
#pragma unroll
        for (int t = 0; t < 10; ++t) acc[r][t] = 0.0f;

    for (int k0 = 0; k0 < KT; k0 += 32) {
        bf16x8 ah[R], al[R];
#pragma unroll
        for (int r = 0; r < R; ++r) {
            size_t ga = (size_t)(row0 + r * 16 + l15) * KT + k0 + q * 8;
            ah[r] = *(const bf16x8*)&Ah[ga];
            al[r] = *(const bf16x8*)&Al[ga];
        }
        union { uint32_t u[4]; uint4 v; } w;
        w.v = *(const uint4*)&Bp[(k0 / 8 + q) * 136 + l15 * 8];
#pragma unroll
        for (int t = 0; t < 10; ++t) {
            union { uint32_t u[4]; bf16x8 h; } bh;
#pragma unroll
            for (int j = 0; j < 4; ++j)
                bh.u[j] = ((w.u[j] >> t) & 0x00010001u) * 0x3F80u;
#pragma unroll
            for (int r = 0; r < R; ++r) {
                acc[r][t] = __builtin_amdgcn_mfma_f32_16x16x32_bf16(ah[r], bh.h, acc[r][t], 0, 0, 0);
                acc[r][t] = __builtin_amdgcn_mfma_f32_16x16x32_bf16(al[r], bh.h, acc[r][t], 0, 0, 0);
            }
        }
    }

    // ---- epilogue ----
    const int tok = l15;
#pragma unroll
    for (int r = 0; r < R; ++r) {
#pragma unroll
        for (int reg = 0; reg < 4; ++reg) {
            const int row = row0 + r * 16 + q * 4 + reg;
            const float bsv = bias[row];
            u16 sv = 0;
            if constexpr (EPI == EP_OUT) sv = Sr[(size_t)b * 8192 + (size_t)row * 16 + tok];
            float mem = 0.0f;
            u16 msk = 0;
#pragma unroll
            for (int t = 0; t < 10; ++t) {
                float u = acc[r][t][reg] + bsv;
                mem += (u - mem) * 0.5f;
                bool s = mem > 1.0f;
                if (s) mem = 0.0f;
                msk |= (u16)((s ? 1u : 0u) << t);
                if constexpr (EPI == EP_OUT) {
                    size_t off = (size_t)(t * B_ + b) * 8192 + (size_t)row * 16 + tok;
                    Oout[off] = Xr[off] + (float)((sv >> t) & 1) + (s ? 1.0f : 0.0f);
                }
            }
            if constexpr (EPI == EP_SPK) {
                O0[(size_t)b * 8192 + (size_t)row * 16 + tok] = msk;
            }
        }
    }
}

// ---------------------------------------------------------------------------
// Temporal scan v5: t-bit-packed I/O, static-index conv, and
// __launch_bounds__(256, 1) so wreg[80] stays in VGPRs (the (256,2) builds
// were pinned at 128 VGPRs and spilled 380 MB of scratch traffic).
// ---------------------------------------------------------------------------
__global__ __launch_bounds__(256, 1) void scan_kernel(
    const u16* __restrict__ qs, const u16* __restrict__ ks,
    const u16* __restrict__ vs, const float* __restrict__ tiw,
    const float* __restrict__ tib, u16* __restrict__ y1pk) {
    __shared__ float qS[4][36 * 20];   // [d+2][m] spike carry, halo rows = 0
    __shared__ float kS[4][32 * 20];
    __shared__ float vS[4][32 * 20];
    __shared__ float qbS[4][32 * 20];
    __shared__ float A[4][16 * 17];
    const int l  = threadIdx.x & 63;
    const int w  = threadIdx.x >> 6;
    const int b  = blockIdx.y;
    const int h  = blockIdx.x * 4 + w;
    const int n  = l & 15, dg = l >> 4;
    float* qSw  = qS[w];
    float* kSw  = kS[w];
    float* vSw  = vS[w];
    float* qbSw = qbS[w];
    float* Aw   = A[w];

    float wreg[80];
#pragma unroll
    for (int j = 0; j < 80; ++j) wreg[j] = tiw[n * 80 + j];
    const float tibr = tib[n];

    if (l < 40) { qSw[l] = 0.0f; qSw[680 + l] = 0.0f; }

    const size_t base = (size_t)b * 8192 + (size_t)h * 512 + (size_t)l * 8;
    union { u16 s[8]; uint4 v; } qw, kw, vw;
    qw.v = *(const uint4*)&qs[base];
    kw.v = *(const uint4*)&ks[base];
    vw.v = *(const uint4*)&vs[base];

#pragma unroll
    for (int j = 0; j < 8; ++j) {
        int f = l * 8 + j, d = f >> 4, m = f & 15;
        qSw[(d + 2) * 20 + m] = (float)(qw.s[j] & 1);
        kSw[d * 20 + m]       = (float)(kw.s[j] & 1);
        vSw[d * 20 + m]       = (float)(vw.s[j] & 1);
    }

    float mem1[8] = {}, mem2[8] = {}, mem3[8] = {};
    u16 ym[8] = {};

    auto attn_step = [&](int t) {
        float dots[4] = {0.0f, 0.0f, 0.0f, 0.0f};
#pragma unroll
        for (int d = 0; d < 32; ++d) {
            float qv = qSw[(d + 2) * 20 + n];
#pragma unroll
            for (int jj = 0; jj < 4; ++jj)
                dots[jj] = fmaf(qv, kSw[d * 20 + dg * 4 + jj], dots[jj]);
        }
#pragma unroll
        for (int jj = 0; jj < 4; ++jj) Aw[n * 17 + dg * 4 + jj] = dots[jj] * 0.25f;
        float o[8] = {};
#pragma unroll
        for (int m = 0; m < 16; ++m) {
            float av = Aw[n * 17 + m];
#pragma unroll
            for (int dd = 0; dd < 8; ++dd)
                o[dd] = fmaf(av, vSw[(dg * 8 + dd) * 20 + m], o[dd]);
        }
#pragma unroll
        for (int dd = 0; dd < 8; ++dd) {
            mem3[dd] += (o[dd] - mem3[dd]) * 0.5f;
            bool s3 = mem3[dd] > 1.0f;
            if (s3) mem3[dd] = 0.0f;
            ym[dd] |= (u16)((s3 ? 1u : 0u) << t);
        }
    };

    attn_step(0);

    for (int t = 1; t < T_; ++t) {
#pragma unroll
        for (int j = 0; j < 8; ++j) {
            int f = l * 8 + j, d = f >> 4, m = f & 15;
            qbSw[d * 20 + m] = (float)((qw.s[j] >> t) & 1);
            kSw[d * 20 + m]  = (float)((kw.s[j] >> t) & 1);
            vSw[d * 20 + m]  = (float)((vw.s[j] >> t) & 1);
        }
        float c[8];
#pragma unroll
        for (int dd = 0; dd < 8; ++dd) c[dd] = tibr;
#pragma unroll
        for (int x = 0; x < 12; ++x) {
            const float* rp = &qSw[(dg * 8 + x) * 20];
            float qrow[16];
            *(float4*)&qrow[0]  = *(const float4*)&rp[0];
            *(float4*)&qrow[4]  = *(const float4*)&rp[4];
            *(float4*)&qrow[8]  = *(const float4*)&rp[8];
            *(float4*)&qrow[12] = *(const float4*)&rp[12];
#pragma unroll
            for (int k = 0; k < 5; ++k) {
                const int o = x - k;
                if (o >= 0 && o < 8) {
#pragma unroll
                    for (int i = 0; i < 16; ++i)
                        c[o] = fmaf(wreg[i * 5 + k], qrow[i], c[o]);
                }
            }
        }
#pragma unroll
        for (int dd = 0; dd < 8; ++dd) {
            mem1[dd] += (c[dd] - mem1[dd]) * 0.5f;
            bool s1 = mem1[dd] > 1.0f;
            if (s1) mem1[dd] = 0.0f;
            float qb = qbSw[(dg * 8 + dd) * 20 + n];
            float mix = 0.5f * (s1 ? 1.0f : 0.0f) + 0.5f * qb;
            mem2[dd] += (mix - mem2[dd]) * 0.5f;
            bool s2 = mem2[dd] > 1.0f;
            if (s2) mem2[dd] = 0.0f;
            qSw[(dg * 8 + dd + 2) * 20 + n] = s2 ? 1.0f : 0.0f;
        }
        attn_step(t);
    }

    union { u16 s[8]; uint4 v; } yv;
#pragma unroll
    for (int dd = 0; dd < 8; ++dd) yv.s[dd] = ym[dd];
    *(uint4*)&y1pk[((size_t)b * 16 + n) * 512 + h * 32 + dg * 8] = yv.v;
}

// ---------------------------------------------------------------------------
extern "C" void kernel_launch(void* const* d_in, const int* in_sizes, int n_in,
                              void* d_out, int out_size, void* d_ws, size_t ws_size,
                              hipStream_t stream) {
    const float* x    = (const float*)d_in[0];
    const float* Wq   = (const float*)d_in[1];
    const float* Wk   = (const float*)d_in[2];
    const float* Wv   = (const float*)d_in[3];
    const float* Wp   = (const float*)d_in[4];
    const float* bnq  = (const float*)d_in[5];
    const float* bnk  = (const float*)d_in[6];
    const float* bnv  = (const float*)d_in[7];
    const float* bnpj = (const float*)d_in[8];
    const float* tiw  = (const float*)d_in[9];
    const float* tib  = (const float*)d_in[10];
    const float* W1   = (const float*)d_in[11];
    const float* b1   = (const float*)d_in[12];
    const float* bn1  = (const float*)d_in[13];
    const float* W2   = (const float*)d_in[14];
    const float* b2   = (const float*)d_in[15];
    const float* bn2  = (const float*)d_in[16];
    float* out = (float*)d_out;

    char* ws = (char*)d_ws;
    size_t cur = 0;
    auto alloc = [&](size_t bytes) -> void* {
        void* p = ws + cur;
        cur = (cur + bytes + 255) & ~(size_t)255;
        return p;
    };
    const size_t PKQ = (size_t)B_ * 8192;          // u16 elems per packed tensor (2 MB)
    u16* qpk  = (u16*)alloc(4 * PKQ * 2);
    u16* kpk  = qpk + PKQ;
    u16* vpk  = qpk + 2 * PKQ;
    u16* y1pk = qpk + 3 * PKQ;
    u16* hspk = qpk;                                // [b*16+n][2048] u16 = 4*PKQ
    u16* spk  = (u16*)alloc(PKQ * 2);               // sproj packed, 2 MB
    short* BhT = (short*)alloc((size_t)TB_ * 16 * 512 * 2);  // 21 MB
    short* BlT = (short*)alloc((size_t)TB_ * 16 * 512 * 2);  // 21 MB
    short* Ah_qkv = (short*)alloc((size_t)1536 * 512 * 2);
    short* Al_qkv = (short*)alloc((size_t)1536 * 512 * 2);
    short* Ah_p   = (short*)alloc((size_t)512 * 512 * 2);
    short* Al_p   = (short*)alloc((size_t)512 * 512 * 2);
    short* Ah_1   = (short*)alloc((size_t)2048 * 512 * 2);
    short* Al_1   = (short*)alloc((size_t)2048 * 512 * 2);
    short* Ah_2   = (short*)alloc((size_t)512 * 2048 * 2);
    short* Al_2   = (short*)alloc((size_t)512 * 2048 * 2);
    float* bs_qkv = (float*)alloc(1536 * 4);
    float* bs_p   = (float*)alloc(512 * 4);
    float* bs_1   = (float*)alloc(2048 * 4);
    float* bs_2   = (float*)alloc(512 * 4);
    // total ~65 MB

    // --- prep: fold BN, split bf16 hi/lo, [m][K] ---
    fold2<<<1024, 256, 0, stream>>>(Wq, bnq, nullptr, 512, 512, 0,    Ah_qkv, Al_qkv, bs_qkv);
    fold2<<<1024, 256, 0, stream>>>(Wk, bnk, nullptr, 512, 512, 512,  Ah_qkv, Al_qkv, bs_qkv);
    fold2<<<1024, 256, 0, stream>>>(Wv, bnv, nullptr, 512, 512, 1024, Ah_qkv, Al_qkv, bs_qkv);
    fold2<<<1024, 256, 0, stream>>>(Wp, bnpj, nullptr, 512, 512, 0,   Ah_p, Al_p, bs_p);
    fold2<<<4096, 256, 0, stream>>>(W1, bn1, b1, 2048, 512, 0,        Ah_1, Al_1, bs_1);
    fold2<<<4096, 256, 0, stream>>>(W2, bn2, b2, 512, 2048, 0,        Ah_2, Al_2, bs_2);

    // --- SSA ---
    splitx<<<TB_, 256, 0, stream>>>(x, nullptr, BhT, BlT);
    gemm_bf16t<2, 12, EP_QKV><<<12 * B_, 256, 0, stream>>>(
        Ah_qkv, Al_qkv, bs_qkv, BhT, BlT, qpk, kpk, vpk);
    scan_kernel<<<dim3(4, B_), 256, 0, stream>>>(qpk, kpk, vpk, tiw, tib, y1pk);
    gemm_pkt<2, 4, EP_SPK, 512><<<4 * B_, 256, 0, stream>>>(
        Ah_p, Al_p, bs_p, y1pk, spk, nullptr, nullptr, nullptr);

    // --- MLP ---  (x2 = x + sproj pre-split once, reusing BhT/BlT)
    splitx<<<TB_, 256, 0, stream>>>(x, spk, BhT, BlT);
    gemm_bf16t<2, 16, EP_HS><<<16 * B_, 256, 0, stream>>>(
        Ah_1, Al_1, bs_1, BhT, BlT, hspk, nullptr, nullptr);
    gemm_pkt<2, 4, EP_OUT, 2048><<<4 * B_, 256, 0, stream>>>(
        Ah_2, Al_2, bs_2, hspk, nullptr, out, x, spk);
}

// Round 9
// 563.095 us; speedup vs baseline: 2.4365x; 1.0126x over previous
//
#include <hip/hip_runtime.h>
#include <cstdint>
#include <cstddef>

#define T_   10
#define B_   128
#define CH_  512
#define N_   16
#define H_   16
#define HID_ 2048
#define TB_  (T_ * B_)       // 1280 (t,b) slabs

#define EP_QKV  0   // u16 t-masks scattered to q/k/v pk buffers in scan layout
#define EP_SPK  1   // u16 t-masks, [b][row*16+tok] (sproj packed)
#define EP_HS   2   // u16 t-masks, [b*16+tok][2048] (hsT packed)
#define EP_OUT  3   // fp32 out = x + sproj + spike (per-t, required layout)

typedef __attribute__((ext_vector_type(8))) short bf16x8;
typedef __attribute__((ext_vector_type(4))) float f32x4;
typedef unsigned short u16;
typedef unsigned long long u64;

__device__ __forceinline__ short f2b(float f) {      // fp32 -> bf16 bits, RNE
    uint32_t u = __float_as_uint(f);
    return (short)((u + 0x7FFFu + ((u >> 16) & 1u)) >> 16);
}
__device__ __forceinline__ float b2f(short s) {
    return __uint_as_float(((uint32_t)(uint16_t)s) << 16);
}

// ---------------------------------------------------------------------------
// Fold BN (+opt conv bias) into weights; emit bf16 hi/lo, [m][K] k-contig.
// ---------------------------------------------------------------------------
__global__ void fold2(const float* __restrict__ W, const float* __restrict__ bnp,
                      const float* __restrict__ eb, int M, int K, int o0,
                      short* __restrict__ Ah, short* __restrict__ Al,
                      float* __restrict__ bias) {
    int idx = blockIdx.x * 256 + threadIdx.x;
    if (idx >= M * K) return;
    int o = idx / K, k = idx - o * K;
    float g  = bnp[o];
    float be = bnp[M + o];
    float mu = bnp[2 * M + o];
    float va = bnp[3 * M + o];
    float inv = g * (1.0f / sqrtf(va + 1e-5f));
    float w = W[idx] * inv;
    short h = f2b(w);
    Ah[(size_t)(o0 + o) * K + k] = h;
    Al[(size_t)(o0 + o) * K + k] = f2b(w - b2f(h));
    if (k == 0) bias[o0 + o] = ((eb ? eb[o] : 0.0f) - mu) * inv + be;
}

// ---------------------------------------------------------------------------
// One-shot fp32 (+opt packed-spike add, bit t) -> bf16 hi/lo split, T-layout
// [slab*16+n][512] (k-contiguous). Bitwise-identical to the in-GEMM split.
// ---------------------------------------------------------------------------
__global__ __launch_bounds__(256) void splitx(
    const float* __restrict__ X, const u16* __restrict__ S,
    short* __restrict__ Bh, short* __restrict__ Bl) {
    __shared__ float xs[8192];
    const int slab = blockIdx.x;
    const int tid  = threadIdx.x;
    const int t    = slab / B_;
    const int b    = slab - t * B_;
    const float* xp = X + (size_t)slab * 8192;
    for (int i = tid; i < 2048; i += 256) {
        float4 v = *(const float4*)&xp[i * 4];
        if (S) {
            union { u16 s[4]; uint2 v; } sw;
            sw.v = *(const uint2*)&S[(size_t)b * 8192 + i * 4];
            v.x += (float)((sw.s[0] >> t) & 1);
            v.y += (float)((sw.s[1] >> t) & 1);
            v.z += (float)((sw.s[2] >> t) & 1);
            v.w += (float)((sw.s[3] >> t) & 1);
        }
        *(float4*)&xs[i * 4] = v;
    }
    __syncthreads();
    const int n = tid & 15, kc = tid >> 4;   // row token n, k-chunk of 32
    size_t orow = ((size_t)slab * 16 + n) * 512 + kc * 32;
#pragma unroll
    for (int i8 = 0; i8 < 4; ++i8) {
        union { short s[8]; uint4 v; } hb, lb;
#pragma unroll
        for (int j = 0; j < 8; ++j) {
            float v = xs[(kc * 32 + i8 * 8 + j) * 16 + n];
            short h = f2b(v);
            hb.s[j] = h;
            lb.s[j] = f2b(v - b2f(h));
        }
        *(uint4*)&Bh[orow + i8 * 8] = hb.v;
        *(uint4*)&Bl[orow + i8 * 8] = lb.v;
    }
}

// ---------------------------------------------------------------------------
// BF16T GEMM v3: k0-outer lockstep loop (proven), R=2, plus
//  (1) double-buffered B LDS -> ONE barrier per k-step (the implicit
//      lgkmcnt(0) in __syncthreads makes this race-free: buf[c] written
//      in iter i is only re-read in iter i, re-written in iter i+2, and
//      every wave's reads complete before its next barrier);
//  (2) A fragments prefetched one k-step ahead into registers, so the
//      post-barrier L2 latency (~200-400cy/k-step at MfmaUtil 42%) is off
//      the critical path.
// Same staged values, k-order, 3-MFMA hi/lo sequence -> bitwise identical.
// ---------------------------------------------------------------------------
template <int R, int GX, int EPI>
__global__ __launch_bounds__(256, 2) void gemm_bf16t(
    const short* __restrict__ Ah, const short* __restrict__ Al,
    const float* __restrict__ bias,
    const short* __restrict__ Bh, const short* __restrict__ Bl,
    u16* __restrict__ O0, u16* __restrict__ O1, u16* __restrict__ O2) {
    constexpr int KT = 512;
    __shared__ __align__(16) short BsH[2][6400];   // [buf][t*16+n][k32], pitch 40
    __shared__ __align__(16) short BsL[2][6400];
    const int tid  = threadIdx.x;
    const int lane = tid & 63;
    const int wv   = tid >> 6;
    const int fid  = blockIdx.x;
    const int xcd  = fid & 7;
    const int slot = fid >> 3;
    const int brow = slot / GX;
    const int xb   = slot - brow * GX;
    const int b    = (brow << 3) | xcd;
    const int l15  = lane & 15;
    const int q    = lane >> 4;
    const int row0 = xb * (R * 64) + wv * (R * 16);

    // staging chunk ids for this thread (640 x 16B chunks per k-step)
    const int i0 = tid, i1 = tid + 256, i2 = tid + 512;   // i2 only if tid<128
    auto gaddr = [&](int idx, int k0) -> size_t {
        int qu = idx & 3, n = (idx >> 2) & 15, t = idx >> 6;
        return ((size_t)(t * B_ + b) * 16 + n) * KT + k0 + qu * 8;
    };
    auto laddr = [&](int idx) -> int {
        int qu = idx & 3, n = (idx >> 2) & 15, t = idx >> 6;
        return (t * 16 + n) * 40 + qu * 8;
    };

    f32x4 acc[R][10];
#pragma unroll
    for (int r = 0; r < R; ++r)
#pragma unroll
        for (int t = 0; t < 10; ++t) acc[r][t] = 0.0f;

    // ---- prologue prefetch: B chunk and A fragments for k0 = 0 ----
    uint4 ph0, ph1, ph2, pl0, pl1, pl2;
    ph0 = *(const uint4*)&Bh[gaddr(i0, 0)];
    pl0 = *(const uint4*)&Bl[gaddr(i0, 0)];
    ph1 = *(const uint4*)&Bh[gaddr(i1, 0)];
    pl1 = *(const uint4*)&Bl[gaddr(i1, 0)];
    if (tid < 128) {
        ph2 = *(const uint4*)&Bh[gaddr(i2, 0)];
        pl2 = *(const uint4*)&Bl[gaddr(i2, 0)];
    }
    bf16x8 ahc[R], alc[R], ahn[R], aln[R];
#pragma unroll
    for (int r = 0; r < R; ++r) {
        size_t ga = (size_t)(row0 + r * 16 + l15) * KT + q * 8;
        ahc[r] = *(const bf16x8*)&Ah[ga];
        alc[r] = *(const bf16x8*)&Al[ga];
    }

    int cur = 0;
    for (int k0 = 0; k0 < KT; k0 += 32) {
        // ---- commit prefetched B chunk to buf[cur] (ds_write only) ----
        *(uint4*)&BsH[cur][laddr(i0)] = ph0;
        *(uint4*)&BsL[cur][laddr(i0)] = pl0;
        *(uint4*)&BsH[cur][laddr(i1)] = ph1;
        *(uint4*)&BsL[cur][laddr(i1)] = pl1;
        if (tid < 128) {
            *(uint4*)&BsH[cur][laddr(i2)] = ph2;
            *(uint4*)&BsL[cur][laddr(i2)] = pl2;
        }
        __syncthreads();   // single barrier per k-step (dbuf)
        // ---- issue next k-step's B and A loads; latency hides under MFMA ----
        if (k0 + 32 < KT) {
            ph0 = *(const uint4*)&Bh[gaddr(i0, k0 + 32)];
            pl0 = *(const uint4*)&Bl[gaddr(i0, k0 + 32)];
            ph1 = *(const uint4*)&Bh[gaddr(i1, k0 + 32)];
            pl1 = *(const uint4*)&Bl[gaddr(i1, k0 + 32)];
            if (tid < 128) {
                ph2 = *(const uint4*)&Bh[gaddr(i2, k0 + 32)];
                pl2 = *(const uint4*)&Bl[gaddr(i2, k0 + 32)];
            }
#pragma unroll
            for (int r = 0; r < R; ++r) {
                size_t ga = (size_t)(row0 + r * 16 + l15) * KT + (k0 + 32) + q * 8;
                ahn[r] = *(const bf16x8*)&Ah[ga];
                aln[r] = *(const bf16x8*)&Al[ga];
            }
        }
        // ---- MFMA over 10 t from buf[cur] with prefetched A ----
#pragma unroll
        for (int t = 0; t < 10; ++t) {
            bf16x8 bh = *(const bf16x8*)&BsH[cur][(t * 16 + l15) * 40 + q * 8];
            bf16x8 bl = *(const bf16x8*)&BsL[cur][(t * 16 + l15) * 40 + q * 8];
#pragma unroll
            for (int r = 0; r < R; ++r) {
                acc[r][t] = __builtin_amdgcn_mfma_f32_16x16x32_bf16(ahc[r], bh, acc[r][t], 0, 0, 0);
                acc[r][t] = __builtin_amdgcn_mfma_f32_16x16x32_bf16(alc[r], bh, acc[r][t], 0, 0, 0);
                acc[r][t] = __builtin_amdgcn_mfma_f32_16x16x32_bf16(ahc[r], bl, acc[r][t], 0, 0, 0);
            }
        }
#pragma unroll
        for (int r = 0; r < R; ++r) { ahc[r] = ahn[r]; alc[r] = aln[r]; }
        cur ^= 1;
    }

    // ---- epilogue: lane holds (row = q*4+reg, tok = l15) x all 10 t ----
    const int tok = l15;
#pragma unroll
    for (int r = 0; r < R; ++r) {
        u16 m4[4];
#pragma unroll
        for (int reg = 0; reg < 4; ++reg) {
            const int row = row0 + r * 16 + q * 4 + reg;
            const float bsv = bias[row];
            float mem = 0.0f;
            u16 msk = 0;
#pragma unroll
            for (int t = 0; t < 10; ++t) {
                float u = acc[r][t][reg] + bsv;
                mem += (u - mem) * 0.5f;
                bool s = mem > 1.0f;
                if (s) mem = 0.0f;
                msk |= (u16)((s ? 1u : 0u) << t);
            }
            if constexpr (EPI == EP_QKV) {
                int tsr = row >> 9;
                int c   = row & 511;
                int hh  = (c & 31) >> 1;
                int dd  = ((c & 1) << 4) | tok;
                int nn  = c >> 5;
                u16* qp = (tsr == 0) ? O0 : ((tsr == 1) ? O1 : O2);
                qp[(size_t)b * 8192 + (size_t)hh * 512 + dd * 16 + nn] = msk;
            } else {  // EP_HS
                m4[reg] = msk;
            }
        }
        if constexpr (EPI == EP_HS) {
            union { u16 s[4]; uint2 v; } pk;
            pk.s[0] = m4[0]; pk.s[1] = m4[1]; pk.s[2] = m4[2]; pk.s[3] = m4[3];
            *(uint2*)&O0[((size_t)b * 16 + tok) * 2048 + row0 + r * 16 + q * 4] = pk.v;
        }
    }
}

// ---------------------------------------------------------------------------
// PKT GEMM, zero-barrier K-loop (round-6, proven): whole packed B panel
// [16n][K] u16 in LDS once ([kc][n][8] u16, slab stride 136), ONE barrier,
// then ds_read_b128 + bit-extract + MFMA with no synchronization -- waves
// free-run and hide all load latency. ((w>>t)&0x00010001)*0x3F80 produces
// exactly the same 0/0x3F80 bf16 values as before.
// ---------------------------------------------------------------------------
template <int R, int GX, int EPI, int KT>
__global__ __launch_bounds__(256, 2) void gemm_pkt(
    const short* __restrict__ Ah, const short* __restrict__ Al,
    const float* __restrict__ bias, const u16* __restrict__ Bu,
    u16* __restrict__ O0, float* __restrict__ Oout,
    const float* __restrict__ Xr, const u16* __restrict__ Sr) {
    constexpr int K8 = KT / 8;
    __shared__ __align__(16) u16 Bp[K8 * 136];
    const int tid  = threadIdx.x;
    const int lane = tid & 63;
    const int wv   = tid >> 6;
    const int fid  = blockIdx.x;
    const int xcd  = fid & 7;
    const int slot = fid >> 3;
    const int brow = slot / GX;
    const int xb   = slot - brow * GX;
    const int b    = (brow << 3) | xcd;
    const int l15  = lane & 15;
    const int q    = lane >> 4;
    const int row0 = xb * (R * 64) + wv * (R * 16);

    // ---- fill packed B panel into LDS (once) ----
    for (int idx = tid; idx < 16 * K8; idx += 256) {
        int kc = idx & (K8 - 1), n = idx / K8;
        *(uint4*)&Bp[kc * 136 + n * 8] =
            *(const uint4*)&Bu[((size_t)b * 16 + n) * KT + kc * 8];
    }
    __syncthreads();   // the only barrier

    f32x4 acc[R][10];
#pragma unroll
    for (int r = 0; r < R; ++r)
#pragma unroll
        for (int t = 0; t < 10; ++t) acc[r][t] = 0.0f;

    for (int k0 = 0; k0 < KT; k0 += 32) {
        bf16x8 ah[R], al[R];
#pragma unroll
        for (int r = 0; r < R; ++r) {
            size_t ga = (size_t)(row0 + r * 16 + l15) * KT + k0 + q * 8;
            ah[r] = *(const bf16x8*)&Ah[ga];
            al[r] = *(const bf16x8*)&Al[ga];
        }
        union { uint32_t u[4]; uint4 v; } w;
        w.v = *(const uint4*)&Bp[(k0 / 8 + q) * 136 + l15 * 8];
#pragma unroll
        for (int t = 0; t < 10; ++t) {
            union { uint32_t u[4]; bf16x8 h; } bh;
#pragma unroll
            for (int j = 0; j < 4; ++j)
                bh.u[j] = ((w.u[j] >> t) & 0x00010001u) * 0x3F80u;
#pragma unroll
            for (int r = 0; r < R; ++r) {
                acc[r][t] = __builtin_amdgcn_mfma_f32_16x16x32_bf16(ah[r], bh.h, acc[r][t], 0, 0, 0);
                acc[r][t] = __builtin_amdgcn_mfma_f32_16x16x32_bf16(al[r], bh.h, acc[r][t], 0, 0, 0);
            }
        }
    }

    // ---- epilogue ----
    const int tok = l15;
#pragma unroll
    for (int r = 0; r < R; ++r) {
#pragma unroll
        for (int reg = 0; reg < 4; ++reg) {
            const int row = row0 + r * 16 + q * 4 + reg;
            const float bsv = bias[row];
            u16 sv = 0;
            if constexpr (EPI == EP_OUT) sv = Sr[(size_t)b * 8192 + (size_t)row * 16 + tok];
            float mem = 0.0f;
            u16 msk = 0;
#pragma unroll
            for (int t = 0; t < 10; ++t) {
                float u = acc[r][t][reg] + bsv;
                mem += (u - mem) * 0.5f;
                bool s = mem > 1.0f;
                if (s) mem = 0.0f;
                msk |= (u16)((s ? 1u : 0u) << t);
                if constexpr (EPI == EP_OUT) {
                    size_t off = (size_t)(t * B_ + b) * 8192 + (size_t)row * 16 + tok;
                    Oout[off] = Xr[off] + (float)((sv >> t) & 1) + (s ? 1.0f : 0.0f);
                }
            }
            if constexpr (EPI == EP_SPK) {
                O0[(size_t)b * 8192 + (size_t)row * 16 + tok] = msk;
            }
        }
    }
}

// ---------------------------------------------------------------------------
// Temporal scan v5: t-bit-packed I/O, static-index conv, and
// __launch_bounds__(256, 1) so wreg[80] stays in VGPRs (the (256,2) builds
// were pinned at 128 VGPRs and spilled 380 MB of scratch traffic).
// ---------------------------------------------------------------------------
__global__ __launch_bounds__(256, 1) void scan_kernel(
    const u16* __restrict__ qs, const u16* __restrict__ ks,
    const u16* __restrict__ vs, const float* __restrict__ tiw,
    const float* __restrict__ tib, u16* __restrict__ y1pk) {
    __shared__ float qS[4][36 * 20];   // [d+2][m] spike carry, halo rows = 0
    __shared__ float kS[4][32 * 20];
    __shared__ float vS[4][32 * 20];
    __shared__ float qbS[4][32 * 20];
    __shared__ float A[4][16 * 17];
    const int l  = threadIdx.x & 63;
    const int w  = threadIdx.x >> 6;
    const int b  = blockIdx.y;
    const int h  = blockIdx.x * 4 + w;
    const int n  = l & 15, dg = l >> 4;
    float* qSw  = qS[w];
    float* kSw  = kS[w];
    float* vSw  = vS[w];
    float* qbSw = qbS[w];
    float* Aw   = A[w];

    float wreg[80];
#pragma unroll
    for (int j = 0; j < 80; ++j) wreg[j] = tiw[n * 80 + j];
    const float tibr = tib[n];

    if (l < 40) { qSw[l] = 0.0f; qSw[680 + l] = 0.0f; }

    const size_t base = (size_t)b * 8192 + (size_t)h * 512 + (size_t)l * 8;
    union { u16 s[8]; uint4 v; } qw, kw, vw;
    qw.v = *(const uint4*)&qs[base];
    kw.v = *(const uint4*)&ks[base];
    vw.v = *(const uint4*)&vs[base];

#pragma unroll
    for (int j = 0; j < 8; ++j) {
        int f = l * 8 + j, d = f >> 4, m = f & 15;
        qSw[(d + 2) * 20 + m] = (float)(qw.s[j] & 1);
        kSw[d * 20 + m]       = (float)(kw.s[j] & 1);
        vSw[d * 20 + m]       = (float)(vw.s[j] & 1);
    }

    float mem1[8] = {}, mem2[8] = {}, mem3[8] = {};
    u16 ym[8] = {};

    auto attn_step = [&](int t) {
        float dots[4] = {0.0f, 0.0f, 0.0f, 0.0f};
#pragma unroll
        for (int d = 0; d < 32; ++d) {
            float qv = qSw[(d + 2) * 20 + n];
#pragma unroll
            for (int jj = 0; jj < 4; ++jj)
                dots[jj] = fmaf(qv, kSw[d * 20 + dg * 4 + jj], dots[jj]);
        }
#pragma unroll
        for (int jj = 0; jj < 4; ++jj) Aw[n * 17 + dg * 4 + jj] = dots[jj] * 0.25f;
        float o[8] = {};
#pragma unroll
        for (int m = 0; m < 16; ++m) {
            float av = Aw[n * 17 + m];
#pragma unroll
            for (int dd = 0; dd < 8; ++dd)
                o[dd] = fmaf(av, vSw[(dg * 8 + dd) * 20 + m], o[dd]);
        }
#pragma unroll
        for (int dd = 0; dd < 8; ++dd) {
            mem3[dd] += (o[dd] - mem3[dd]) * 0.5f;
            bool s3 = mem3[dd] > 1.0f;
            if (s3) mem3[dd] = 0.0f;
            ym[dd] |= (u16)((s3 ? 1u : 0u) << t);
        }
    };

    attn_step(0);

    for (int t = 1; t < T_; ++t) {
#pragma unroll
        for (int j = 0; j < 8; ++j) {
            int f = l * 8 + j, d = f >> 4, m = f & 15;
            qbSw[d * 20 + m] = (float)((qw.s[j] >> t) & 1);
            kSw[d * 20 + m]  = (float)((kw.s[j] >> t) & 1);
            vSw[d * 20 + m]  = (float)((vw.s[j] >> t) & 1);
        }
        float c[8];
#pragma unroll
        for (int dd = 0; dd < 8; ++dd) c[dd] = tibr;
#pragma unroll
        for (int x = 0; x < 12; ++x) {
            const float* rp = &qSw[(dg * 8 + x) * 20];
            float qrow[16];
            *(float4*)&qrow[0]  = *(const float4*)&rp[0];
            *(float4*)&qrow[4]  = *(const float4*)&rp[4];
            *(float4*)&qrow[8]  = *(const float4*)&rp[8];
            *(float4*)&qrow[12] = *(const float4*)&rp[12];
#pragma unroll
            for (int k = 0; k < 5; ++k) {
                const int o = x - k;
                if (o >= 0 && o < 8) {
#pragma unroll
                    for (int i = 0; i < 16; ++i)
                        c[o] = fmaf(wreg[i * 5 + k], qrow[i], c[o]);
                }
            }
        }
#pragma unroll
        for (int dd = 0; dd < 8; ++dd) {
            mem1[dd] += (c[dd] - mem1[dd]) * 0.5f;
            bool s1 = mem1[dd] > 1.0f;
            if (s1) mem1[dd] = 0.0f;
            float qb = qbSw[(dg * 8 + dd) * 20 + n];
            float mix = 0.5f * (s1 ? 1.0f : 0.0f) + 0.5f * qb;
            mem2[dd] += (mix - mem2[dd]) * 0.5f;
            bool s2 = mem2[dd] > 1.0f;
            if (s2) mem2[dd] = 0.0f;
            qSw[(dg * 8 + dd + 2) * 20 + n] = s2 ? 1.0f : 0.0f;
        }
        attn_step(t);
    }

    union { u16 s[8]; uint4 v; } yv;
#pragma unroll
    for (int dd = 0; dd < 8; ++dd) yv.s[dd] = ym[dd];
    *(uint4*)&y1pk[((size_t)b * 16 + n) * 512 + h * 32 + dg * 8] = yv.v;
}

// ---------------------------------------------------------------------------
extern "C" void kernel_launch(void* const* d_in, const int* in_sizes, int n_in,
                              void* d_out, int out_size, void* d_ws, size_t ws_size,
                              hipStream_t stream) {
    const float* x    = (const float*)d_in[0];
    const float* Wq   = (const float*)d_in[1];
    const float* Wk   = (const float*)d_in[2];
    const float* Wv   = (const float*)d_in[3];
    const float* Wp   = (const float*)d_in[4];
    const float* bnq  = (const float*)d_in[5];
    const float* bnk  = (const float*)d_in[6];
    const float* bnv  = (const float*)d_in[7];
    const float* bnpj = (const float*)d_in[8];
    const float* tiw  = (const float*)d_in[9];
    const float* tib  = (const float*)d_in[10];
    const float* W1   = (const float*)d_in[11];
    const float* b1   = (const float*)d_in[12];
    const float* bn1  = (const float*)d_in[13];
    const float* W2   = (const float*)d_in[14];
    const float* b2   = (const float*)d_in[15];
    const float* bn2  = (const float*)d_in[16];
    float* out = (float*)d_out;

    char* ws = (char*)d_ws;
    size_t cur = 0;
    auto alloc = [&](size_t bytes) -> void* {
        void* p = ws + cur;
        cur = (cur + bytes + 255) & ~(size_t)255;
        return p;
    };
    const size_t PKQ = (size_t)B_ * 8192;          // u16 elems per packed tensor (2 MB)
    u16* qpk  = (u16*)alloc(4 * PKQ * 2);
    u16* kpk  = qpk + PKQ;
    u16* vpk  = qpk + 2 * PKQ;
    u16* y1pk = qpk + 3 * PKQ;
    u16* hspk = qpk;                                // [b*16+n][2048] u16 = 4*PKQ
    u16* spk  = (u16*)alloc(PKQ * 2);               // sproj packed, 2 MB
    short* BhT = (short*)alloc((size_t)TB_ * 16 * 512 * 2);  // 21 MB
    short* BlT = (short*)alloc((size_t)TB_ * 16 * 512 * 2);  // 21 MB
    short* Ah_qkv = (short*)alloc((size_t)1536 * 512 * 2);
    short* Al_qkv = (short*)alloc((size_t)1536 * 512 * 2);
    short* Ah_p   = (short*)alloc((size_t)512 * 512 * 2);
    short* Al_p   = (short*)alloc((size_t)512 * 512 * 2);
    short* Ah_1   = (short*)alloc((size_t)2048 * 512 * 2);
    short* Al_1   = (short*)alloc((size_t)2048 * 512 * 2);
    short* Ah_2   = (short*)alloc((size_t)512 * 2048 * 2);
    short* Al_2   = (short*)alloc((size_t)512 * 2048 * 2);
    float* bs_qkv = (float*)alloc(1536 * 4);
    float* bs_p   = (float*)alloc(512 * 4);
    float* bs_1   = (float*)alloc(2048 * 4);
    float* bs_2   = (float*)alloc(512 * 4);
    // total ~65 MB

    // --- prep: fold BN, split bf16 hi/lo, [m][K] ---
    fold2<<<1024, 256, 0, stream>>>(Wq, bnq, nullptr, 512, 512, 0,    Ah_qkv, Al_qkv, bs_qkv);
    fold2<<<1024, 256, 0, stream>>>(Wk, bnk, nullptr, 512, 512, 512,  Ah_qkv, Al_qkv, bs_qkv);
    fold2<<<1024, 256, 0, stream>>>(Wv, bnv, nullptr, 512, 512, 1024, Ah_qkv, Al_qkv, bs_qkv);
    fold2<<<1024, 256, 0, stream>>>(Wp, bnpj, nullptr, 512, 512, 0,   Ah_p, Al_p, bs_p);
    fold2<<<4096, 256, 0, stream>>>(W1, bn1, b1, 2048, 512, 0,        Ah_1, Al_1, bs_1);
    fold2<<<4096, 256, 0, stream>>>(W2, bn2, b2, 512, 2048, 0,        Ah_2, Al_2, bs_2);

    // --- SSA ---
    splitx<<<TB_, 256, 0, stream>>>(x, nullptr, BhT, BlT);
    gemm_bf16t<2, 12, EP_QKV><<<12 * B_, 256, 0, stream>>>(
        Ah_qkv, Al_qkv, bs_qkv, BhT, BlT, qpk, kpk, vpk);
    scan_kernel<<<dim3(4, B_), 256, 0, stream>>>(qpk, kpk, vpk, tiw, tib, y1pk);
    gemm_pkt<2, 4, EP_SPK, 512><<<4 * B_, 256, 0, stream>>>(
        Ah_p, Al_p, bs_p, y1pk, spk, nullptr, nullptr, nullptr);

    // --- MLP ---  (x2 = x + sproj pre-split once, reusing BhT/BlT)
    splitx<<<TB_, 256, 0, stream>>>(x, spk, BhT, BlT);
    gemm_bf16t<2, 16, EP_HS><<<16 * B_, 256, 0, stream>>>(
        Ah_1, Al_1, bs_1, BhT, BlT, hspk, nullptr, nullptr);
    gemm_pkt<2, 4, EP_OUT, 2048><<<4 * B_, 256, 0, stream>>>(
        Ah_2, Al_2, bs_2, hspk, nullptr, out, x, spk);
}